// Round 2
// baseline (9381.750 us; speedup 1.0000x reference)
//
#include <hip/hip_runtime.h>
#include <hip/hip_bf16.h>

// ---------------- constants (match reference) ----------------
static constexpr int NA = 50000;   // atoms
static constexpr int NE = 400000;  // edges
static constexpr int HD = 128;     // hidden
static constexpr int NRBF = 20;
static constexpr int NL = 4;       // layers
static constexpr int NM = 500;     // molecules

typedef __hip_bfloat16 bf16;
__device__ __forceinline__ float tof(bf16 x) { return __bfloat162float(x); }
__device__ __forceinline__ bf16  tob(float x) { return __float2bfloat16(x); }
__device__ __forceinline__ float silu_f(float x) {
    float sg = 1.0f / (1.0f + __expf(-x));
    return x * sg;
}

// ---------------- geometry: dist, dirs ----------------
__global__ void geom_kernel(const float* __restrict__ pos,
                            const int* __restrict__ row, const int* __restrict__ col,
                            float* __restrict__ dist_g, float* __restrict__ dirs) {
    int e = blockIdx.x * 256 + threadIdx.x;
    if (e >= NE) return;
    int r = row[e], c = col[e];
    float dx = pos[c*3+0] - pos[r*3+0];
    float dy = pos[c*3+1] - pos[r*3+1];
    float dz = pos[c*3+2] - pos[r*3+2];
    float dist = sqrtf(dx*dx + dy*dy + dz*dz);
    float inv = 1.0f / (dist + 1e-8f);
    dist_g[e] = dist;
    dirs[e*3+0] = dx*inv; dirs[e*3+1] = dy*inv; dirs[e*3+2] = dz*inv;
}

// ---------------- CSR build ----------------
__global__ void deg_kernel(const int* __restrict__ row, int* __restrict__ deg) {
    int e = blockIdx.x * 256 + threadIdx.x;
    if (e >= NE) return;
    atomicAdd(&deg[row[e]], 1);
}

__global__ __launch_bounds__(1024) void scan_kernel(const int* __restrict__ deg,
                                                    int* __restrict__ row_ptr,
                                                    int* __restrict__ cursor) {
    __shared__ int sh[1024];
    __shared__ int carry_sh;
    int t = threadIdx.x;
    if (t == 0) { carry_sh = 0; row_ptr[0] = 0; }
    __syncthreads();
    for (int base = 0; base < NA; base += 1024) {
        int x = (base + t < NA) ? deg[base + t] : 0;
        sh[t] = x;
        __syncthreads();
        for (int off = 1; off < 1024; off <<= 1) {
            int v_ = (t >= off) ? sh[t - off] : 0;
            __syncthreads();
            sh[t] += v_;
            __syncthreads();
        }
        int incl = sh[t];
        int carry = carry_sh;
        if (base + t < NA) {
            row_ptr[base + t + 1] = carry + incl;
            cursor[base + t] = carry + incl - x;  // exclusive = row start
        }
        __syncthreads();
        if (t == 1023) carry_sh = carry + incl;
        __syncthreads();
    }
}

__global__ void scatter_kernel(const int* __restrict__ row, int* __restrict__ cursor,
                               int* __restrict__ csr_eid) {
    int e = blockIdx.x * 256 + threadIdx.x;
    if (e >= NE) return;
    int p = atomicAdd(&cursor[row[e]], 1);
    csr_eid[p] = e;
}

// ---------------- node init: s = emb[z], v = 0 ----------------
__global__ void embed_kernel(const int* __restrict__ z, const float* __restrict__ emb,
                             float* __restrict__ s, bf16* __restrict__ v) {
    int idx = blockIdx.x * 256 + threadIdx.x;
    if (idx >= NA * HD) return;
    int n = idx >> 7, c = idx & 127;
    s[idx] = emb[z[n] * HD + c];
    bf16* vb = v + ((size_t)n * HD + c) * 3;
    bf16 z16 = tob(0.f);
    vb[0] = z16; vb[1] = z16; vb[2] = z16;
}

// ---------------- filter MLP for a chunk of CSR-ordered edges ----------------
// h[e,384] = silu(rbf(dist[e])@W1 + b1) @ W2 + b2; rbf recomputed from dist.
__global__ __launch_bounds__(384) void filter_kernel(
    const float* __restrict__ dist_g, const int* __restrict__ csr_eid,
    const int* __restrict__ row_ptr,
    const float* __restrict__ W1, const float* __restrict__ b1,
    const float* __restrict__ W2, const float* __restrict__ b2,
    float* __restrict__ h_chunk, int node_start, int node_end, int cap)
{
    __shared__ float rbf_s[64 * 21];   // padded stride 21
    __shared__ float w1_s[NRBF * HD];  // 20x128
    __shared__ float t_tr[HD * 64];    // transposed t: [k][e]
    __shared__ float dist_s[64];

    int tid = threadIdx.x;
    int e_start = row_ptr[node_start];
    int e_end = row_ptr[node_end];
    int base = blockIdx.x * 64;  // chunk-local edge base
    int n_e = e_end - e_start - base;
    if (n_e <= 0) return;
    if (n_e > 64) n_e = 64;

    if (tid < 64) {
        int p = (tid < n_e) ? (e_start + base + tid) : (e_start + base);
        dist_s[tid] = dist_g[csr_eid[p]];
    }
    for (int i = tid; i < NRBF * HD; i += 384) w1_s[i] = W1[i];
    __syncthreads();

    for (int i = tid; i < 64 * NRBF; i += 384) {
        int e = i / NRBF, k = i - e * NRBF;
        float d = dist_s[e] - (5.0f / 19.0f) * (float)k;
        rbf_s[e * 21 + k] = __expf(-d * d);
    }
    __syncthreads();

    // GEMM1 + silu -> t_tr[k2][e]
    for (int i = tid; i < HD * 64; i += 384) {
        int k2 = i >> 6, e = i & 63;
        float acc = b1[k2];
#pragma unroll
        for (int k = 0; k < NRBF; ++k) acc += rbf_s[e * 21 + k] * w1_s[k * HD + k2];
        t_tr[k2 * 64 + e] = silu_f(acc);
    }
    __syncthreads();

    // GEMM2: thread owns output column o, 64 edge accumulators
    int o = tid;
    float acc[64];
#pragma unroll
    for (int e = 0; e < 64; ++e) acc[e] = 0.f;
    for (int k = 0; k < HD; ++k) {
        float w = W2[k * 384 + o];
        const float4* t4 = (const float4*)(&t_tr[k * 64]);
#pragma unroll
        for (int e4 = 0; e4 < 16; ++e4) {
            float4 tv = t4[e4];
            acc[e4*4+0] += tv.x * w;
            acc[e4*4+1] += tv.y * w;
            acc[e4*4+2] += tv.z * w;
            acc[e4*4+3] += tv.w * w;
        }
    }
    float bias = b2[o];
    for (int e = 0; e < n_e; ++e) {
        int le = base + e;
        if (le < cap) h_chunk[(size_t)le * 384 + o] = acc[e] + bias;
    }
}

// ---------------- per-node aggregation (no atomics) ----------------
__global__ __launch_bounds__(128) void aggregate_kernel(
    const float* __restrict__ h_chunk, const int* __restrict__ csr_eid,
    const int* __restrict__ row_ptr, const int* __restrict__ col,
    const float* __restrict__ dirs, const float* __restrict__ s,
    const bf16* __restrict__ v, float* __restrict__ m_s, bf16* __restrict__ m_v,
    int node_start, int cap)
{
    int n = node_start + blockIdx.x;
    int c = threadIdx.x;
    int e0 = row_ptr[n], e1 = row_ptr[n + 1];
    int ch_e0 = row_ptr[node_start];
    float as = 0.f, av0 = 0.f, av1 = 0.f, av2 = 0.f;
    for (int p = e0; p < e1; ++p) {
        int lp = p - ch_e0;
        if (lp >= cap) break;  // statistically impossible; guards OOB
        const float* hb = h_chunk + (size_t)lp * 384;
        float pss = hb[c], pvv = hb[128 + c], psv = hb[256 + c];
        int eid = csr_eid[p];
        int ci = col[eid];
        float sc = s[(size_t)ci * HD + c];
        float d0 = dirs[eid*3+0], d1 = dirs[eid*3+1], d2 = dirs[eid*3+2];
        const bf16* vb = v + ((size_t)ci * HD + c) * 3;
        float svd = psv * sc;
        as  += pss * sc;
        av0 += pvv * tof(vb[0]) + svd * d0;
        av1 += pvv * tof(vb[1]) + svd * d1;
        av2 += pvv * tof(vb[2]) + svd * d2;
    }
    m_s[(size_t)n * HD + c] = as;
    bf16* mvb = m_v + ((size_t)n * HD + c) * 3;
    mvb[0] = tob(av0); mvb[1] = tob(av1); mvb[2] = tob(av2);
}

// ---------------- update GEMM1 (fused concat): t1 = silu([s,m_s,|m_v|] @ W1 + b1) ----------------
__global__ __launch_bounds__(256) void upd_gemm1(
    const float* __restrict__ s, const float* __restrict__ m_s,
    const bf16* __restrict__ m_v, const float* __restrict__ W1,
    const float* __restrict__ b1, float* __restrict__ t1)
{
    __shared__ float A_tr[64 * 68];  // [k-chunk 64][rows 64], stride 68
    int tid = threadIdx.x;
    int o = tid & 127, eh = tid >> 7;
    int r0 = blockIdx.x * 64;
    float acc[32];
#pragma unroll
    for (int e = 0; e < 32; ++e) acc[e] = 0.f;
    for (int kc = 0; kc < 6; ++kc) {
        __syncthreads();
        for (int i = tid; i < 4096; i += 256) {
            int k = i & 63, e = i >> 6;
            int r = r0 + e; if (r >= NA) r = NA - 1;
            int kk = kc * 64 + k;
            float val;
            if (kk < 128) {
                val = s[(size_t)r * HD + kk];
            } else if (kk < 256) {
                val = m_s[(size_t)r * HD + (kk - 128)];
            } else {
                int c = kk - 256;
                const bf16* mvb = m_v + ((size_t)r * HD + c) * 3;
                float x = tof(mvb[0]), y = tof(mvb[1]), z = tof(mvb[2]);
                val = sqrtf(x*x + y*y + z*z);
            }
            A_tr[k * 68 + e] = val;
        }
        __syncthreads();
        for (int k = 0; k < 64; ++k) {
            float w = W1[(kc * 64 + k) * HD + o];
            const float4* a4 = (const float4*)(&A_tr[k * 68 + eh * 32]);
#pragma unroll
            for (int e4 = 0; e4 < 8; ++e4) {
                float4 av = a4[e4];
                acc[e4*4+0] += av.x * w; acc[e4*4+1] += av.y * w;
                acc[e4*4+2] += av.z * w; acc[e4*4+3] += av.w * w;
            }
        }
    }
    float bias = b1[o];
    for (int e = 0; e < 32; ++e) {
        int r = r0 + eh * 32 + e;
        if (r < NA) t1[(size_t)r * HD + o] = silu_f(acc[e] + bias);
    }
}

// ---------------- update GEMM2 (fused epilogue): u = t1 @ W2 + b2; s += ds; v = a*v + b*m_v ----------------
__global__ __launch_bounds__(384) void upd_gemm2(
    const float* __restrict__ t1, const float* __restrict__ W2,
    const float* __restrict__ b2, const bf16* __restrict__ m_v,
    float* __restrict__ s, bf16* __restrict__ v)
{
    __shared__ float t_tr[HD * 68];  // [k 128][row 64]; epilogue aliases alpha (8192 <= 8704)
    float* alpha_s = t_tr;
    int tid = threadIdx.x;
    int r0 = blockIdx.x * 64;
    for (int i = tid; i < HD * 64; i += 384) {
        int k = i & 127, e = i >> 7;
        int r = r0 + e; if (r >= NA) r = NA - 1;
        t_tr[k * 68 + e] = t1[(size_t)r * HD + k];
    }
    __syncthreads();
    int o = tid;
    float acc[64];
#pragma unroll
    for (int e = 0; e < 64; ++e) acc[e] = 0.f;
    for (int k = 0; k < HD; ++k) {
        float w = W2[k * 384 + o];
        const float4* t4 = (const float4*)(&t_tr[k * 68]);
#pragma unroll
        for (int e4 = 0; e4 < 16; ++e4) {
            float4 tv = t4[e4];
            acc[e4*4+0] += tv.x * w; acc[e4*4+1] += tv.y * w;
            acc[e4*4+2] += tv.z * w; acc[e4*4+3] += tv.w * w;
        }
    }
    float bias = b2[o];
    __syncthreads();  // all t_tr reads done before aliasing as alpha
    if (o >= 128 && o < 256) {
        int c = o - 128;
#pragma unroll
        for (int e = 0; e < 64; ++e) alpha_s[e * 128 + c] = acc[e] + bias;
    }
    __syncthreads();
    if (o < 128) {
        for (int e = 0; e < 64; ++e) {
            int r = r0 + e;
            if (r < NA) s[(size_t)r * HD + o] += acc[e] + bias;
        }
    } else if (o >= 256) {
        int c = o - 256;
        for (int e = 0; e < 64; ++e) {
            int r = r0 + e;
            if (r >= NA) break;
            float al = alpha_s[e * 128 + c];
            float be = acc[e] + bias;
            size_t ix = ((size_t)r * HD + c) * 3;
            v[ix+0] = tob(al * tof(v[ix+0]) + be * tof(m_v[ix+0]));
            v[ix+1] = tob(al * tof(v[ix+1]) + be * tof(m_v[ix+1]));
            v[ix+2] = tob(al * tof(v[ix+2]) + be * tof(m_v[ix+2]));
        }
    }
}

// ---------------- readout: per-molecule mean + two MLP heads ----------------
__global__ __launch_bounds__(128) void readout_kernel(
    const float* __restrict__ s, const int* __restrict__ batch,
    const float* __restrict__ lamW1, const float* __restrict__ lamb1,
    const float* __restrict__ lamW2, const float* __restrict__ lamb2,
    const float* __restrict__ phiW1, const float* __restrict__ phib1,
    const float* __restrict__ phiW2, const float* __restrict__ phib2,
    float* __restrict__ out)
{
    __shared__ int seg[2];
    __shared__ float hms[HD];
    __shared__ float red[HD];
    int m = blockIdx.x, c = threadIdx.x;
    if (c < 2) {
        int target = m + c;
        int lo = 0, hi = NA;
        while (lo < hi) { int mid = (lo + hi) >> 1; if (batch[mid] < target) lo = mid + 1; else hi = mid; }
        seg[c] = lo;
    }
    __syncthreads();
    int st = seg[0], en = seg[1];
    float acc = 0.f;
    for (int n2 = st; n2 < en; ++n2) acc += s[(size_t)n2 * HD + c];
    float hm = acc / (float)(en - st);
    hms[c] = hm;
    __syncthreads();

    // lam head
    float t = lamb1[c];
    for (int k = 0; k < HD; ++k) t += hms[k] * lamW1[k * HD + c];
    t = silu_f(t);
    red[c] = t * lamW2[c];
    __syncthreads();
    for (int off = 64; off > 0; off >>= 1) { if (c < off) red[c] += red[c + off]; __syncthreads(); }
    if (c == 0) out[m] = red[0] + lamb2[0];
    __syncthreads();

    // phi head
    t = phib1[c];
    for (int k = 0; k < HD; ++k) t += hms[k] * phiW1[k * HD + c];
    t = silu_f(t);
    red[c] = t * phiW2[c];
    __syncthreads();
    for (int off = 64; off > 0; off >>= 1) { if (c < off) red[c] += red[c + off]; __syncthreads(); }
    if (c == 0) { float x = red[0] + phib2[0]; out[NM + m] = 1.0f / (1.0f + __expf(-x)); }
}

// ---------------- host ----------------
extern "C" void kernel_launch(void* const* d_in, const int* in_sizes, int n_in,
                              void* d_out, int out_size, void* d_ws, size_t ws_size,
                              hipStream_t stream) {
    (void)in_sizes; (void)n_in; (void)out_size;
    const int*   z          = (const int*)  d_in[0];
    const float* pos        = (const float*)d_in[1];
    const int*   edge_index = (const int*)  d_in[2];
    const int*   batch      = (const int*)  d_in[3];
    const float* emb        = (const float*)d_in[4];
    const float* filt_W1    = (const float*)d_in[5];
    const float* filt_b1    = (const float*)d_in[6];
    const float* filt_W2    = (const float*)d_in[7];
    const float* filt_b2    = (const float*)d_in[8];
    const float* upd_W1     = (const float*)d_in[9];
    const float* upd_b1     = (const float*)d_in[10];
    const float* upd_W2     = (const float*)d_in[11];
    const float* upd_b2     = (const float*)d_in[12];
    const float* lam_W1     = (const float*)d_in[13];
    const float* lam_b1     = (const float*)d_in[14];
    const float* lam_W2     = (const float*)d_in[15];
    const float* lam_b2     = (const float*)d_in[16];
    const float* phi_W1     = (const float*)d_in[17];
    const float* phi_b1     = (const float*)d_in[18];
    const float* phi_W2     = (const float*)d_in[19];
    const float* phi_b2     = (const float*)d_in[20];
    float* out = (float*)d_out;

    const int* row = edge_index;
    const int* col = edge_index + NE;

    char* ws = (char*)d_ws;
    size_t off = 0;
    auto alloc = [&](size_t bytes) -> char* {
        char* p = ws + off;
        off = (off + bytes + 255) & ~(size_t)255;
        return p;
    };
    // fixed footprint ~155 MiB
    float* dist_g  = (float*)alloc((size_t)NE * 4);
    float* dirs    = (float*)alloc((size_t)NE * 3 * 4);
    int*   csr_eid = (int*)  alloc((size_t)NE * 4);
    int*   row_ptr = (int*)  alloc((size_t)(NA + 1) * 4);
    int*   deg     = (int*)  alloc((size_t)NA * 4);
    int*   cursor  = (int*)  alloc((size_t)NA * 4);
    float* s       = (float*)alloc((size_t)NA * HD * 4);
    bf16*  v       = (bf16*) alloc((size_t)NA * HD * 3 * 2);
    float* m_s     = (float*)alloc((size_t)NA * HD * 4);
    bf16*  m_v     = (bf16*) alloc((size_t)NA * HD * 3 * 2);
    float* t1      = (float*)alloc((size_t)NA * HD * 4);

    size_t rem = (ws_size > off) ? (ws_size - off) : 0;
    int C, cap;
    if      (rem >= (size_t)32768 * 384 * 4) { C = 16;  cap = 32768; }
    else if (rem >= (size_t)16384 * 384 * 4) { C = 32;  cap = 16384; }
    else if (rem >= (size_t)8192  * 384 * 4) { C = 64;  cap = 8192;  }
    else                                     { C = 256; cap = 2048;  }
    float* h_chunk = (float*)(ws + off);

    const int EB = (NE + 255) / 256;   // edge-parallel blocks
    const int NB = (NA * HD) / 256;    // node*channel blocks (25000, exact)

    hipMemsetAsync(deg, 0, (size_t)NA * 4, stream);
    geom_kernel<<<EB, 256, 0, stream>>>(pos, row, col, dist_g, dirs);
    deg_kernel<<<EB, 256, 0, stream>>>(row, deg);
    scan_kernel<<<1, 1024, 0, stream>>>(deg, row_ptr, cursor);
    scatter_kernel<<<EB, 256, 0, stream>>>(row, cursor, csr_eid);
    embed_kernel<<<NB, 256, 0, stream>>>(z, emb, s, v);

    int npc = (NA + C - 1) / C;
    for (int i = 0; i < NL; ++i) {
        const float* fW1 = filt_W1 + (size_t)i * NRBF * HD;
        const float* fb1 = filt_b1 + (size_t)i * HD;
        const float* fW2 = filt_W2 + (size_t)i * HD * 384;
        const float* fb2 = filt_b2 + (size_t)i * 384;
        const float* uW1 = upd_W1 + (size_t)i * 384 * HD;
        const float* ub1 = upd_b1 + (size_t)i * HD;
        const float* uW2 = upd_W2 + (size_t)i * HD * 384;
        const float* ub2 = upd_b2 + (size_t)i * 384;

        for (int ch = 0; ch < C; ++ch) {
            int ns = ch * npc;
            if (ns >= NA) break;
            int ne = ns + npc; if (ne > NA) ne = NA;
            filter_kernel<<<cap / 64, 384, 0, stream>>>(
                dist_g, csr_eid, row_ptr, fW1, fb1, fW2, fb2, h_chunk, ns, ne, cap);
            aggregate_kernel<<<ne - ns, 128, 0, stream>>>(
                h_chunk, csr_eid, row_ptr, col, dirs, s, v, m_s, m_v, ns, cap);
        }
        upd_gemm1<<<(NA + 63) / 64, 256, 0, stream>>>(s, m_s, m_v, uW1, ub1, t1);
        upd_gemm2<<<(NA + 63) / 64, 384, 0, stream>>>(t1, uW2, ub2, m_v, s, v);
    }

    readout_kernel<<<NM, 128, 0, stream>>>(s, batch,
        lam_W1, lam_b1, lam_W2, lam_b2,
        phi_W1, phi_b1, phi_W2, phi_b2, out);
}

// Round 3
// 4640.914 us; speedup vs baseline: 2.0215x; 2.0215x over previous
//
#include <hip/hip_runtime.h>
#include <hip/hip_bf16.h>

// ---------------- constants (match reference) ----------------
static constexpr int NA = 50000;   // atoms
static constexpr int NE = 400000;  // edges
static constexpr int HD = 128;     // hidden
static constexpr int NL = 4;       // layers
static constexpr int NM = 500;     // molecules

typedef __hip_bfloat16 bf16;
typedef short short8 __attribute__((ext_vector_type(8)));
typedef float float4v __attribute__((ext_vector_type(4)));

__device__ __forceinline__ float tof(bf16 x) { return __bfloat162float(x); }
__device__ __forceinline__ bf16  tob(float x) { return __float2bfloat16(x); }
__device__ __forceinline__ unsigned short f2bf_bits(float x) {
    union { float f; unsigned int u; } c; c.f = x;
    unsigned int lsb = (c.u >> 16) & 1u;
    return (unsigned short)((c.u + 0x7fffu + lsb) >> 16);
}
__device__ __forceinline__ float silu_f(float x) {
    float sg = 1.0f / (1.0f + __expf(-x));
    return x * sg;
}

// ---------------- geometry: dist, dirs ----------------
__global__ void geom_kernel(const float* __restrict__ pos,
                            const int* __restrict__ row, const int* __restrict__ col,
                            float* __restrict__ dist_g, float* __restrict__ dirs) {
    int e = blockIdx.x * 256 + threadIdx.x;
    if (e >= NE) return;
    int r = row[e], c = col[e];
    float dx = pos[c*3+0] - pos[r*3+0];
    float dy = pos[c*3+1] - pos[r*3+1];
    float dz = pos[c*3+2] - pos[r*3+2];
    float dist = sqrtf(dx*dx + dy*dy + dz*dz);
    float inv = 1.0f / (dist + 1e-8f);
    dist_g[e] = dist;
    dirs[e*3+0] = dx*inv; dirs[e*3+1] = dy*inv; dirs[e*3+2] = dz*inv;
}

// ---------------- CSR build ----------------
__global__ void deg_kernel(const int* __restrict__ row, int* __restrict__ deg) {
    int e = blockIdx.x * 256 + threadIdx.x;
    if (e >= NE) return;
    atomicAdd(&deg[row[e]], 1);
}

__global__ __launch_bounds__(1024) void scan_kernel(const int* __restrict__ deg,
                                                    int* __restrict__ row_ptr,
                                                    int* __restrict__ cursor) {
    __shared__ int sh[1024];
    __shared__ int carry_sh;
    int t = threadIdx.x;
    if (t == 0) { carry_sh = 0; row_ptr[0] = 0; }
    __syncthreads();
    for (int base = 0; base < NA; base += 1024) {
        int x = (base + t < NA) ? deg[base + t] : 0;
        sh[t] = x;
        __syncthreads();
        for (int off = 1; off < 1024; off <<= 1) {
            int v_ = (t >= off) ? sh[t - off] : 0;
            __syncthreads();
            sh[t] += v_;
            __syncthreads();
        }
        int incl = sh[t];
        int carry = carry_sh;
        if (base + t < NA) {
            row_ptr[base + t + 1] = carry + incl;
            cursor[base + t] = carry + incl - x;
        }
        __syncthreads();
        if (t == 1023) carry_sh = carry + incl;
        __syncthreads();
    }
}

__global__ void scatter_kernel(const int* __restrict__ row, int* __restrict__ cursor,
                               int* __restrict__ csr_eid) {
    int e = blockIdx.x * 256 + threadIdx.x;
    if (e >= NE) return;
    int p = atomicAdd(&cursor[row[e]], 1);
    csr_eid[p] = e;
}

// ---------------- node init: s = emb[z], v = 0 (v planar [n][3][HD]) ----------------
__global__ void embed_kernel(const int* __restrict__ z, const float* __restrict__ emb,
                             float* __restrict__ s, bf16* __restrict__ v) {
    int idx = blockIdx.x * 256 + threadIdx.x;
    if (idx >= NA * HD) return;
    int n = idx >> 7, c = idx & 127;
    s[idx] = emb[z[n] * HD + c];
    bf16* vb = v + (size_t)n * 3 * HD + c;
    bf16 z16 = tob(0.f);
    vb[0] = z16; vb[HD] = z16; vb[2*HD] = z16;
}

// ---------------- W2 -> B-fragment-linear bf16 layout ----------------
// frag layout: [layer][nt(24)][kc(4)][lane(64)][j(8)], element = W2[k][n],
// n = nt*16 + (lane&15), k = kc*32 + (lane>>4)*8 + j
__global__ void prep_w2frag_kernel(const float* __restrict__ W2all,
                                   unsigned short* __restrict__ frag) {
    int idx = blockIdx.x * 256 + threadIdx.x;   // NL*24*4*64 = 24576 items
    if (idx >= NL * 24 * 4 * 64) return;
    int lane = idx & 63;
    int kc = (idx >> 6) & 3;
    int nt = (idx >> 8) % 24;
    int layer = (idx >> 8) / 24;
    int n = nt * 16 + (lane & 15);
    int k0 = kc * 32 + (lane >> 4) * 8;
    const float* W2 = W2all + (size_t)layer * HD * 384;
    short8 vv;
#pragma unroll
    for (int j = 0; j < 8; ++j)
        vv[j] = (short)f2bf_bits(W2[(size_t)(k0 + j) * 384 + n]);
    *(short8*)(&frag[(size_t)idx * 8]) = vv;
}

// ---------------- filter MLP (MFMA GEMM2) for 64 CSR-ordered edges/block -------------
__global__ __launch_bounds__(256) void filter_mfma_kernel(
    const float* __restrict__ dist_g, const int* __restrict__ csr_eid,
    const int* __restrict__ row_ptr,
    const float* __restrict__ W1, const float* __restrict__ b1,
    const unsigned short* __restrict__ W2frag, const float* __restrict__ b2,
    float* __restrict__ h_chunk, int node_start, int node_end, int cap)
{
    __shared__ float dist_s[64];
    __shared__ float w1_s[20 * HD];                        // 10 KB
    __shared__ __align__(16) unsigned short t_frag[16 * 64 * 8]; // 16 KB, A-frag linear

    int tid = threadIdx.x;
    int e_start = row_ptr[node_start];
    int e_end = row_ptr[node_end];
    int base = blockIdx.x * 64;
    int n_e = e_end - e_start - base;
    if (n_e <= 0 || base >= cap) return;
    if (n_e > 64) n_e = 64;

    if (tid < 64) {
        int p = (tid < n_e) ? (e_start + base + tid) : (e_start + base);
        dist_s[tid] = dist_g[csr_eid[p]];
    }
    for (int i = tid; i < 20 * HD; i += 256) w1_s[i] = W1[i];
    __syncthreads();

    int lane = tid & 63, w = tid >> 6;

    // ---- GEMM1 (VALU): wave w computes k2 in [w*32, w*32+32) for edge=lane ----
    {
        float d = dist_s[lane];
        float rk[20];
#pragma unroll
        for (int k = 0; k < 20; ++k) { float t = d - (5.0f/19.0f)*(float)k; rk[k] = __expf(-t*t); }
        float acc[32];
#pragma unroll
        for (int m = 0; m < 32; ++m) acc[m] = b1[w*32 + m];
#pragma unroll
        for (int k = 0; k < 20; ++k) {
            const float4* wrow = (const float4*)(&w1_s[k * HD + w * 32]);
            float r = rk[k];
#pragma unroll
            for (int m4 = 0; m4 < 8; ++m4) {
                float4 wv = wrow[m4];
                acc[m4*4+0] += r * wv.x; acc[m4*4+1] += r * wv.y;
                acc[m4*4+2] += r * wv.z; acc[m4*4+3] += r * wv.w;
            }
        }
        // pack silu(acc) into A-frag layout: frag idx ((edge>>4)*4 + kc=w)*64 + hi*16 + (edge&15)
#pragma unroll
        for (int hi = 0; hi < 4; ++hi) {
            short8 vv;
#pragma unroll
            for (int j = 0; j < 8; ++j)
                vv[j] = (short)f2bf_bits(silu_f(acc[hi*8 + j]));
            int fi = (((lane >> 4) * 4 + w) * 64 + hi * 16 + (lane & 15)) * 8;
            *(short8*)(&t_frag[fi]) = vv;
        }
    }
    __syncthreads();

    // ---- GEMM2 (MFMA): wave w computes edges [16w,16w+16) x N=384, K=128 ----
    short8 a[4];
#pragma unroll
    for (int kc = 0; kc < 4; ++kc)
        a[kc] = *(const short8*)(&t_frag[((w * 4 + kc) * 64 + lane) * 8]);
    int col = lane & 15, quad = lane >> 4;
    size_t hb = (size_t)base * 384;
    for (int nt = 0; nt < 24; ++nt) {
        float4v acc = {0.f, 0.f, 0.f, 0.f};
#pragma unroll
        for (int kc = 0; kc < 4; ++kc) {
            short8 b = *(const short8*)(W2frag + ((size_t)(nt * 4 + kc) * 64 + lane) * 8);
            acc = __builtin_amdgcn_mfma_f32_16x16x32_bf16(a[kc], b, acc, 0, 0, 0);
        }
        int n = nt * 16 + col;
        float bias = b2[n];
#pragma unroll
        for (int r = 0; r < 4; ++r) {
            int e = 16 * w + quad * 4 + r;
            if (e < n_e)
                h_chunk[hb + (size_t)e * 384 + n] = acc[r] + bias;
        }
    }
}

// ---------------- per-node aggregation (no atomics; planar v/m_v) ----------------
__global__ __launch_bounds__(128) void aggregate_kernel(
    const float* __restrict__ h_chunk, const int* __restrict__ csr_eid,
    const int* __restrict__ row_ptr, const int* __restrict__ col,
    const float* __restrict__ dirs, const float* __restrict__ s,
    const bf16* __restrict__ v, float* __restrict__ m_s, bf16* __restrict__ m_v,
    int node_start, int cap)
{
    int n = node_start + blockIdx.x;
    int c = threadIdx.x;
    int e0 = row_ptr[n], e1 = row_ptr[n + 1];
    int ch_e0 = row_ptr[node_start];
    float as = 0.f, av0 = 0.f, av1 = 0.f, av2 = 0.f;
    for (int p = e0; p < e1; ++p) {
        int lp = p - ch_e0;
        if (lp >= cap) break;
        const float* hb = h_chunk + (size_t)lp * 384;
        float pss = hb[c], pvv = hb[128 + c], psv = hb[256 + c];
        int eid = csr_eid[p];
        int ci = col[eid];
        float sc = s[(size_t)ci * HD + c];
        float d0 = dirs[eid*3+0], d1 = dirs[eid*3+1], d2 = dirs[eid*3+2];
        const bf16* vb = v + (size_t)ci * 3 * HD + c;
        float svd = psv * sc;
        as  += pss * sc;
        av0 += pvv * tof(vb[0])    + svd * d0;
        av1 += pvv * tof(vb[HD])   + svd * d1;
        av2 += pvv * tof(vb[2*HD]) + svd * d2;
    }
    m_s[(size_t)n * HD + c] = as;
    bf16* mvb = m_v + (size_t)n * 3 * HD + c;
    mvb[0] = tob(av0); mvb[HD] = tob(av1); mvb[2*HD] = tob(av2);
}

// ---------------- update GEMM1 (fused concat): t1 = silu([s,m_s,|m_v|] @ W1 + b1) -----
__global__ __launch_bounds__(256) void upd_gemm1(
    const float* __restrict__ s, const float* __restrict__ m_s,
    const bf16* __restrict__ m_v, const float* __restrict__ W1,
    const float* __restrict__ b1, float* __restrict__ t1)
{
    __shared__ float A_tr[64 * 68];
    int tid = threadIdx.x;
    int o = tid & 127, eh = tid >> 7;
    int r0 = blockIdx.x * 64;
    float acc[32];
#pragma unroll
    for (int e = 0; e < 32; ++e) acc[e] = 0.f;
    for (int kc = 0; kc < 6; ++kc) {
        __syncthreads();
        for (int i = tid; i < 4096; i += 256) {
            int k = i & 63, e = i >> 6;
            int r = r0 + e; if (r >= NA) r = NA - 1;
            int kk = kc * 64 + k;
            float val;
            if (kk < 128) {
                val = s[(size_t)r * HD + kk];
            } else if (kk < 256) {
                val = m_s[(size_t)r * HD + (kk - 128)];
            } else {
                int c = kk - 256;
                const bf16* mvb = m_v + (size_t)r * 3 * HD + c;
                float x = tof(mvb[0]), y = tof(mvb[HD]), z = tof(mvb[2*HD]);
                val = sqrtf(x*x + y*y + z*z);
            }
            A_tr[k * 68 + e] = val;
        }
        __syncthreads();
        for (int k = 0; k < 64; ++k) {
            float w = W1[(kc * 64 + k) * HD + o];
            const float4* a4 = (const float4*)(&A_tr[k * 68 + eh * 32]);
#pragma unroll
            for (int e4 = 0; e4 < 8; ++e4) {
                float4 av = a4[e4];
                acc[e4*4+0] += av.x * w; acc[e4*4+1] += av.y * w;
                acc[e4*4+2] += av.z * w; acc[e4*4+3] += av.w * w;
            }
        }
    }
    float bias = b1[o];
    for (int e = 0; e < 32; ++e) {
        int r = r0 + eh * 32 + e;
        if (r < NA) t1[(size_t)r * HD + o] = silu_f(acc[e] + bias);
    }
}

// ---------------- update GEMM2 (fused epilogue): u = t1 @ W2 + b2; s+=ds; v=a*v+b*m_v --
__global__ __launch_bounds__(384) void upd_gemm2(
    const float* __restrict__ t1, const float* __restrict__ W2,
    const float* __restrict__ b2, const bf16* __restrict__ m_v,
    float* __restrict__ s, bf16* __restrict__ v)
{
    __shared__ float t_tr[HD * 68];
    float* alpha_s = t_tr;
    int tid = threadIdx.x;
    int r0 = blockIdx.x * 64;
    for (int i = tid; i < HD * 64; i += 384) {
        int k = i & 127, e = i >> 7;
        int r = r0 + e; if (r >= NA) r = NA - 1;
        t_tr[k * 68 + e] = t1[(size_t)r * HD + k];
    }
    __syncthreads();
    int o = tid;
    float acc[64];
#pragma unroll
    for (int e = 0; e < 64; ++e) acc[e] = 0.f;
    for (int k = 0; k < HD; ++k) {
        float w = W2[k * 384 + o];
        const float4* t4 = (const float4*)(&t_tr[k * 68]);
#pragma unroll
        for (int e4 = 0; e4 < 16; ++e4) {
            float4 tv = t4[e4];
            acc[e4*4+0] += tv.x * w; acc[e4*4+1] += tv.y * w;
            acc[e4*4+2] += tv.z * w; acc[e4*4+3] += tv.w * w;
        }
    }
    float bias = b2[o];
    __syncthreads();
    if (o >= 128 && o < 256) {
        int c = o - 128;
#pragma unroll
        for (int e = 0; e < 64; ++e) alpha_s[e * 128 + c] = acc[e] + bias;
    }
    __syncthreads();
    if (o < 128) {
        for (int e = 0; e < 64; ++e) {
            int r = r0 + e;
            if (r < NA) s[(size_t)r * HD + o] += acc[e] + bias;
        }
    } else if (o >= 256) {
        int c = o - 256;
        for (int e = 0; e < 64; ++e) {
            int r = r0 + e;
            if (r >= NA) break;
            float al = alpha_s[e * 128 + c];
            float be = acc[e] + bias;
            size_t ix = (size_t)r * 3 * HD + c;
            v[ix]        = tob(al * tof(v[ix])        + be * tof(m_v[ix]));
            v[ix+HD]     = tob(al * tof(v[ix+HD])     + be * tof(m_v[ix+HD]));
            v[ix+2*HD]   = tob(al * tof(v[ix+2*HD])   + be * tof(m_v[ix+2*HD]));
        }
    }
}

// ---------------- readout ----------------
__global__ __launch_bounds__(128) void readout_kernel(
    const float* __restrict__ s, const int* __restrict__ batch,
    const float* __restrict__ lamW1, const float* __restrict__ lamb1,
    const float* __restrict__ lamW2, const float* __restrict__ lamb2,
    const float* __restrict__ phiW1, const float* __restrict__ phib1,
    const float* __restrict__ phiW2, const float* __restrict__ phib2,
    float* __restrict__ out)
{
    __shared__ int seg[2];
    __shared__ float hms[HD];
    __shared__ float red[HD];
    int m = blockIdx.x, c = threadIdx.x;
    if (c < 2) {
        int target = m + c;
        int lo = 0, hi = NA;
        while (lo < hi) { int mid = (lo + hi) >> 1; if (batch[mid] < target) lo = mid + 1; else hi = mid; }
        seg[c] = lo;
    }
    __syncthreads();
    int st = seg[0], en = seg[1];
    float acc = 0.f;
    for (int n2 = st; n2 < en; ++n2) acc += s[(size_t)n2 * HD + c];
    float hm = acc / (float)(en - st);
    hms[c] = hm;
    __syncthreads();

    float t = lamb1[c];
    for (int k = 0; k < HD; ++k) t += hms[k] * lamW1[k * HD + c];
    t = silu_f(t);
    red[c] = t * lamW2[c];
    __syncthreads();
    for (int off = 64; off > 0; off >>= 1) { if (c < off) red[c] += red[c + off]; __syncthreads(); }
    if (c == 0) out[m] = red[0] + lamb2[0];
    __syncthreads();

    t = phib1[c];
    for (int k = 0; k < HD; ++k) t += hms[k] * phiW1[k * HD + c];
    t = silu_f(t);
    red[c] = t * phiW2[c];
    __syncthreads();
    for (int off = 64; off > 0; off >>= 1) { if (c < off) red[c] += red[c + off]; __syncthreads(); }
    if (c == 0) { float x = red[0] + phib2[0]; out[NM + m] = 1.0f / (1.0f + __expf(-x)); }
}

// ---------------- host ----------------
extern "C" void kernel_launch(void* const* d_in, const int* in_sizes, int n_in,
                              void* d_out, int out_size, void* d_ws, size_t ws_size,
                              hipStream_t stream) {
    (void)in_sizes; (void)n_in; (void)out_size;
    const int*   z          = (const int*)  d_in[0];
    const float* pos        = (const float*)d_in[1];
    const int*   edge_index = (const int*)  d_in[2];
    const int*   batch      = (const int*)  d_in[3];
    const float* emb        = (const float*)d_in[4];
    const float* filt_W1    = (const float*)d_in[5];
    const float* filt_b1    = (const float*)d_in[6];
    const float* filt_W2    = (const float*)d_in[7];
    const float* filt_b2    = (const float*)d_in[8];
    const float* upd_W1     = (const float*)d_in[9];
    const float* upd_b1     = (const float*)d_in[10];
    const float* upd_W2     = (const float*)d_in[11];
    const float* upd_b2     = (const float*)d_in[12];
    const float* lam_W1     = (const float*)d_in[13];
    const float* lam_b1     = (const float*)d_in[14];
    const float* lam_W2     = (const float*)d_in[15];
    const float* lam_b2     = (const float*)d_in[16];
    const float* phi_W1     = (const float*)d_in[17];
    const float* phi_b1     = (const float*)d_in[18];
    const float* phi_W2     = (const float*)d_in[19];
    const float* phi_b2     = (const float*)d_in[20];
    float* out = (float*)d_out;

    const int* row = edge_index;
    const int* col = edge_index + NE;

    char* ws = (char*)d_ws;
    size_t off = 0;
    auto alloc = [&](size_t bytes) -> char* {
        char* p = ws + off;
        off = (off + bytes + 255) & ~(size_t)255;
        return p;
    };
    float* dist_g  = (float*)alloc((size_t)NE * 4);
    float* dirs    = (float*)alloc((size_t)NE * 3 * 4);
    int*   csr_eid = (int*)  alloc((size_t)NE * 4);
    int*   row_ptr = (int*)  alloc((size_t)(NA + 1) * 4);
    int*   deg     = (int*)  alloc((size_t)NA * 4);
    int*   cursor  = (int*)  alloc((size_t)NA * 4);
    float* s       = (float*)alloc((size_t)NA * HD * 4);
    bf16*  v       = (bf16*) alloc((size_t)NA * HD * 3 * 2);
    float* m_s     = (float*)alloc((size_t)NA * HD * 4);
    bf16*  m_v     = (bf16*) alloc((size_t)NA * HD * 3 * 2);
    float* t1      = (float*)alloc((size_t)NA * HD * 4);
    unsigned short* w2frag = (unsigned short*)alloc((size_t)NL * 24 * 4 * 64 * 8 * 2);

    size_t rem = (ws_size > off) ? (ws_size - off) : 0;
    int C, cap;
    if      (rem >= (size_t)32768 * 384 * 4) { C = 16;  cap = 32768; }
    else if (rem >= (size_t)16384 * 384 * 4) { C = 32;  cap = 16384; }
    else if (rem >= (size_t)8192  * 384 * 4) { C = 64;  cap = 8192;  }
    else                                     { C = 256; cap = 2048;  }
    float* h_chunk = (float*)(ws + off);

    const int EB = (NE + 255) / 256;
    const int NB = (NA * HD) / 256;

    hipMemsetAsync(deg, 0, (size_t)NA * 4, stream);
    geom_kernel<<<EB, 256, 0, stream>>>(pos, row, col, dist_g, dirs);
    deg_kernel<<<EB, 256, 0, stream>>>(row, deg);
    scan_kernel<<<1, 1024, 0, stream>>>(deg, row_ptr, cursor);
    scatter_kernel<<<EB, 256, 0, stream>>>(row, cursor, csr_eid);
    embed_kernel<<<NB, 256, 0, stream>>>(z, emb, s, v);
    prep_w2frag_kernel<<<(NL*24*4*64 + 255)/256, 256, 0, stream>>>(filt_W2, w2frag);

    int npc = (NA + C - 1) / C;
    for (int i = 0; i < NL; ++i) {
        const float* fW1 = filt_W1 + (size_t)i * 20 * HD;
        const float* fb1 = filt_b1 + (size_t)i * HD;
        const float* fb2 = filt_b2 + (size_t)i * 384;
        const unsigned short* fW2f = w2frag + (size_t)i * 24 * 4 * 64 * 8;
        const float* uW1 = upd_W1 + (size_t)i * 384 * HD;
        const float* ub1 = upd_b1 + (size_t)i * HD;
        const float* uW2 = upd_W2 + (size_t)i * HD * 384;
        const float* ub2 = upd_b2 + (size_t)i * 384;

        for (int ch = 0; ch < C; ++ch) {
            int ns = ch * npc;
            if (ns >= NA) break;
            int ne = ns + npc; if (ne > NA) ne = NA;
            filter_mfma_kernel<<<cap / 64, 256, 0, stream>>>(
                dist_g, csr_eid, row_ptr, fW1, fb1, fW2f, fb2, h_chunk, ns, ne, cap);
            aggregate_kernel<<<ne - ns, 128, 0, stream>>>(
                h_chunk, csr_eid, row_ptr, col, dirs, s, v, m_s, m_v, ns, cap);
        }
        upd_gemm1<<<(NA + 63) / 64, 256, 0, stream>>>(s, m_s, m_v, uW1, ub1, t1);
        upd_gemm2<<<(NA + 63) / 64, 384, 0, stream>>>(t1, uW2, ub2, m_v, s, v);
    }

    readout_kernel<<<NM, 128, 0, stream>>>(s, batch,
        lam_W1, lam_b1, lam_W2, lam_b2,
        phi_W1, phi_b1, phi_W2, phi_b2, out);
}

// Round 4
// 2492.884 us; speedup vs baseline: 3.7634x; 1.8617x over previous
//
#include <hip/hip_runtime.h>
#include <hip/hip_bf16.h>

// ---------------- constants (match reference) ----------------
static constexpr int NA = 50000;   // atoms
static constexpr int NE = 400000;  // edges
static constexpr int HD = 128;     // hidden
static constexpr int NL = 4;       // layers
static constexpr int NM = 500;     // molecules

typedef __hip_bfloat16 bf16;
typedef short short8 __attribute__((ext_vector_type(8)));
typedef float float4v __attribute__((ext_vector_type(4)));

__device__ __forceinline__ float tof(bf16 x) { return __bfloat162float(x); }
__device__ __forceinline__ bf16  tob(float x) { return __float2bfloat16(x); }
__device__ __forceinline__ unsigned short f2bf_bits(float x) {
    union { float f; unsigned int u; } c; c.f = x;
    unsigned int lsb = (c.u >> 16) & 1u;
    return (unsigned short)((c.u + 0x7fffu + lsb) >> 16);
}
__device__ __forceinline__ float bf2f(unsigned short b) {
    union { unsigned int u; float f; } c; c.u = ((unsigned int)b) << 16;
    return c.f;
}
__device__ __forceinline__ float silu_f(float x) {
    float sg = 1.0f / (1.0f + __expf(-x));
    return x * sg;
}

// ---------------- geometry: dist, dirs ----------------
__global__ void geom_kernel(const float* __restrict__ pos,
                            const int* __restrict__ row, const int* __restrict__ col,
                            float* __restrict__ dist_g, float* __restrict__ dirs) {
    int e = blockIdx.x * 256 + threadIdx.x;
    if (e >= NE) return;
    int r = row[e], c = col[e];
    float dx = pos[c*3+0] - pos[r*3+0];
    float dy = pos[c*3+1] - pos[r*3+1];
    float dz = pos[c*3+2] - pos[r*3+2];
    float dist = sqrtf(dx*dx + dy*dy + dz*dz);
    float inv = 1.0f / (dist + 1e-8f);
    dist_g[e] = dist;
    dirs[e*3+0] = dx*inv; dirs[e*3+1] = dy*inv; dirs[e*3+2] = dz*inv;
}

// ---------------- CSR build ----------------
__global__ void deg_kernel(const int* __restrict__ row, int* __restrict__ deg) {
    int e = blockIdx.x * 256 + threadIdx.x;
    if (e >= NE) return;
    atomicAdd(&deg[row[e]], 1);
}

__global__ __launch_bounds__(1024) void scan_kernel(const int* __restrict__ deg,
                                                    int* __restrict__ row_ptr,
                                                    int* __restrict__ cursor) {
    __shared__ int sh[1024];
    __shared__ int carry_sh;
    int t = threadIdx.x;
    if (t == 0) { carry_sh = 0; row_ptr[0] = 0; }
    __syncthreads();
    for (int base = 0; base < NA; base += 1024) {
        int x = (base + t < NA) ? deg[base + t] : 0;
        sh[t] = x;
        __syncthreads();
        for (int off = 1; off < 1024; off <<= 1) {
            int v_ = (t >= off) ? sh[t - off] : 0;
            __syncthreads();
            sh[t] += v_;
            __syncthreads();
        }
        int incl = sh[t];
        int carry = carry_sh;
        if (base + t < NA) {
            row_ptr[base + t + 1] = carry + incl;
            cursor[base + t] = carry + incl - x;
        }
        __syncthreads();
        if (t == 1023) carry_sh = carry + incl;
        __syncthreads();
    }
}

__global__ void scatter_kernel(const int* __restrict__ row, int* __restrict__ cursor,
                               int* __restrict__ csr_eid) {
    int e = blockIdx.x * 256 + threadIdx.x;
    if (e >= NE) return;
    int p = atomicAdd(&cursor[row[e]], 1);
    csr_eid[p] = e;
}

// ---------------- node init: s = emb[z], v = 0 (v planar [n][3][HD] bf16) ----------
__global__ void embed_kernel(const int* __restrict__ z, const float* __restrict__ emb,
                             float* __restrict__ s, bf16* __restrict__ v) {
    int idx = blockIdx.x * 256 + threadIdx.x;
    if (idx >= NA * HD) return;
    int n = idx >> 7, c = idx & 127;
    s[idx] = emb[z[n] * HD + c];
    bf16* vb = v + (size_t)n * 3 * HD + c;
    bf16 z16 = tob(0.f);
    vb[0] = z16; vb[HD] = z16; vb[2*HD] = z16;
}

// ---------------- generic weight -> B-fragment-linear bf16 ----------------
// out item idx = ((layer*NT + nt)*KC + kc)*64 + lane; holds 8 shorts:
// W[k0+j][n], n = nt*16 + (lane&15), k0 = kc*32 + (lane>>4)*8
__global__ void pack_bfrag_kernel(const float* __restrict__ W, int K, int N,
                                  int layers, unsigned short* __restrict__ out) {
    int NT = N >> 4, KC = K >> 5;
    int total = layers * NT * KC * 64;
    int idx = blockIdx.x * 256 + threadIdx.x;
    if (idx >= total) return;
    int lane = idx & 63;
    int kc = (idx >> 6) % KC;
    int nt = ((idx >> 6) / KC) % NT;
    int layer = (idx >> 6) / (KC * NT);
    const float* Wl = W + (size_t)layer * K * N;
    int n = nt * 16 + (lane & 15);
    int k0 = kc * 32 + (lane >> 4) * 8;
    short8 pk;
#pragma unroll
    for (int j = 0; j < 8; ++j)
        pk[j] = (short)f2bf_bits(Wl[(size_t)(k0 + j) * N + n]);
    *(short8*)(&out[(size_t)idx * 8]) = pk;
}

// ---------------- fused filter + aggregate: 64 CSR edges per block ----------------
__global__ __launch_bounds__(256) void layer_msg_kernel(
    const float* __restrict__ dist_g, const int* __restrict__ csr_eid,
    const int* __restrict__ row_ptr, const int* __restrict__ row,
    const int* __restrict__ col, const float* __restrict__ dirs,
    const float* __restrict__ W1, const float* __restrict__ b1,
    const unsigned short* __restrict__ W2frag, const float* __restrict__ b2,
    const float* __restrict__ s, const bf16* __restrict__ v,
    float* __restrict__ m_s, float* __restrict__ m_v)
{
    // h LDS: 64 edges x 392 shorts (384 + 8 pad) = 50176 B.
    // Phase 1-2 alias: t_frag (16 KB) at offset 0, w1_s (10 KB) at offset 16K.
    __shared__ __align__(16) char smem[64 * 392 * 2];
    unsigned short* t_frag = (unsigned short*)smem;
    float* w1_s = (float*)(smem + 16384);
    unsigned short* h_l = (unsigned short*)smem;
    __shared__ float dist_s[64];
    __shared__ int   col_s[64];
    __shared__ int   rid_s[64];
    __shared__ float dirs_s[64 * 3];

    int tid = threadIdx.x;
    int base = blockIdx.x * 64;   // CSR position base (NE = 6250*64 exactly)

    if (tid < 64) {
        int eid = csr_eid[base + tid];
        dist_s[tid] = dist_g[eid];
        col_s[tid] = col[eid];
        rid_s[tid] = row[eid];
        dirs_s[tid*3+0] = dirs[eid*3+0];
        dirs_s[tid*3+1] = dirs[eid*3+1];
        dirs_s[tid*3+2] = dirs[eid*3+2];
    }
    for (int i = tid; i < 20 * HD; i += 256) w1_s[i] = W1[i];
    __syncthreads();

    int lane = tid & 63, w = tid >> 6;

    // ---- phase 1: GEMM1 (VALU), edge = lane, out-channels [32w, 32w+32) ----
    {
        float d = dist_s[lane];
        float rk[20];
#pragma unroll
        for (int k = 0; k < 20; ++k) { float t = d - (5.0f/19.0f)*(float)k; rk[k] = __expf(-t*t); }
        float acc[32];
#pragma unroll
        for (int m = 0; m < 32; ++m) acc[m] = b1[w*32 + m];
#pragma unroll
        for (int k = 0; k < 20; ++k) {
            const float4* wrow = (const float4*)(&w1_s[k * HD + w * 32]);
            float r = rk[k];
#pragma unroll
            for (int m4 = 0; m4 < 8; ++m4) {
                float4 wv = wrow[m4];
                acc[m4*4+0] += r * wv.x; acc[m4*4+1] += r * wv.y;
                acc[m4*4+2] += r * wv.z; acc[m4*4+3] += r * wv.w;
            }
        }
        // pack silu(acc) into A-frag: value (edge=lane, k = 32w + hi*8 + j)
#pragma unroll
        for (int hi = 0; hi < 4; ++hi) {
            short8 vv;
#pragma unroll
            for (int j = 0; j < 8; ++j)
                vv[j] = (short)f2bf_bits(silu_f(acc[hi*8 + j]));
            int fi = (((lane >> 4) * 4 + w) * 64 + hi * 16 + (lane & 15)) * 8;
            *(short8*)(&t_frag[fi]) = vv;
        }
    }
    __syncthreads();

    // ---- phase 2: load own A-frags (wave w: edges [16w,16w+16)) ----
    short8 a[4];
#pragma unroll
    for (int kc = 0; kc < 4; ++kc)
        a[kc] = *(const short8*)(&t_frag[((w * 4 + kc) * 64 + lane) * 8]);
    __syncthreads();   // all frag reads done -> smem reusable as h

    // ---- phase 3: MFMA GEMM2, write h (bf16) to LDS ----
    int colb = lane & 15, quad = lane >> 4;
    for (int nt = 0; nt < 24; ++nt) {
        float4v acc = {0.f, 0.f, 0.f, 0.f};
#pragma unroll
        for (int kc = 0; kc < 4; ++kc) {
            short8 b = *(const short8*)(W2frag + ((size_t)(nt * 4 + kc) * 64 + lane) * 8);
            acc = __builtin_amdgcn_mfma_f32_16x16x32_bf16(a[kc], b, acc, 0, 0, 0);
        }
        int n = nt * 16 + colb;
        float bias = b2[n];
#pragma unroll
        for (int r = 0; r < 4; ++r) {
            int e = 16 * w + quad * 4 + r;
            h_l[e * 392 + n] = f2bf_bits(acc[r] + bias);
        }
    }
    __syncthreads();

    // ---- phase 4: per-node aggregation from LDS h ----
    int c = tid & 127, team = tid >> 7;     // 2 teams x 128 channels
    int node_lo = rid_s[0], node_hi = rid_s[63];
    for (int n = node_lo + team; n <= node_hi; n += 2) {
        int p0 = row_ptr[n], p1 = row_ptr[n + 1];
        bool interior = (p0 >= base) && (p1 <= base + 64);
        int lo = p0 > base ? p0 - base : 0;
        int hi = (p1 < base + 64 ? p1 : base + 64) - base;
        float as = 0.f, av0 = 0.f, av1 = 0.f, av2 = 0.f;
        for (int e = lo; e < hi; ++e) {
            float pss = bf2f(h_l[e * 392 + c]);
            float pvv = bf2f(h_l[e * 392 + 128 + c]);
            float psv = bf2f(h_l[e * 392 + 256 + c]);
            int ci = col_s[e];
            float sc = s[(size_t)ci * HD + c];
            const bf16* vb = v + (size_t)ci * 3 * HD + c;
            float d0 = dirs_s[e*3], d1 = dirs_s[e*3+1], d2 = dirs_s[e*3+2];
            float svd = psv * sc;
            as  += pss * sc;
            av0 += pvv * tof(vb[0])    + svd * d0;
            av1 += pvv * tof(vb[HD])   + svd * d1;
            av2 += pvv * tof(vb[2*HD]) + svd * d2;
        }
        size_t ms_ix = (size_t)n * HD + c;
        size_t mv_ix = (size_t)n * 3 * HD + c;
        if (interior) {
            m_s[ms_ix] = as;
            m_v[mv_ix] = av0; m_v[mv_ix + HD] = av1; m_v[mv_ix + 2*HD] = av2;
        } else {
            atomicAdd(&m_s[ms_ix], as);
            atomicAdd(&m_v[mv_ix], av0);
            atomicAdd(&m_v[mv_ix + HD], av1);
            atomicAdd(&m_v[mv_ix + 2*HD], av2);
        }
    }
}

// ---------------- fused update MLP (MFMA x2) + s/v apply: 64 atoms per block -------
__global__ __launch_bounds__(256) void upd12_kernel(
    float* __restrict__ s, bf16* __restrict__ v,
    const float* __restrict__ m_s, const float* __restrict__ m_v,
    const unsigned short* __restrict__ W1frag, const float* __restrict__ b1,
    const unsigned short* __restrict__ W2frag, const float* __restrict__ b2)
{
    // A1-frags: cat[64 rows][384 k] bf16 = 48 KB. t1-frags alias first 16 KB later.
    __shared__ __align__(16) unsigned short afrag[64 * 384];
    int tid = threadIdx.x;
    int r0 = blockIdx.x * 64;

    // ---- stage cat -> A1 frag layout ----
    // 3072 short8 tasks: id -> r = id/48, kg = id%48 (k-group of 8)
#pragma unroll
    for (int t = 0; t < 12; ++t) {
        int id = tid + 256 * t;
        int r = id / 48;
        int kg = id % 48;
        int rr = r0 + r; if (rr >= NA) rr = NA - 1;
        float vals[8];
        if (kg < 16) {
            const float* p = s + (size_t)rr * HD + kg * 8;
#pragma unroll
            for (int j = 0; j < 8; ++j) vals[j] = p[j];
        } else if (kg < 32) {
            const float* p = m_s + (size_t)rr * HD + (kg - 16) * 8;
#pragma unroll
            for (int j = 0; j < 8; ++j) vals[j] = p[j];
        } else {
            int cb = (kg - 32) * 8;
            const float* p = m_v + (size_t)rr * 3 * HD + cb;
#pragma unroll
            for (int j = 0; j < 8; ++j) {
                float x = p[j], y = p[HD + j], z = p[2*HD + j];
                vals[j] = sqrtf(x*x + y*y + z*z);
            }
        }
        int kc = kg >> 2, hi = kg & 3, m = r & 15, rt = r >> 4;
        short8 pk;
#pragma unroll
        for (int j = 0; j < 8; ++j) pk[j] = (short)f2bf_bits(vals[j]);
        *(short8*)(&afrag[(((rt * 12 + kc) * 64) + hi * 16 + m) * 8]) = pk;
    }
    __syncthreads();

    int lane = tid & 63, w = tid >> 6;
    int colb = lane & 15, quad = lane >> 4;

    // ---- MFMA1: t1[64 x 128] = cat @ W1 ----
    float4v acc1[8];
#pragma unroll
    for (int nt = 0; nt < 8; ++nt) acc1[nt] = (float4v){0.f,0.f,0.f,0.f};
    for (int kc = 0; kc < 12; ++kc) {
        short8 a = *(const short8*)(&afrag[((w * 12 + kc) * 64 + lane) * 8]);
#pragma unroll
        for (int nt = 0; nt < 8; ++nt) {
            short8 b = *(const short8*)(W1frag + ((size_t)(nt * 12 + kc) * 64 + lane) * 8);
            acc1[nt] = __builtin_amdgcn_mfma_f32_16x16x32_bf16(a, b, acc1[nt], 0, 0, 0);
        }
    }
    __syncthreads();   // all A1 reads done before overwrite with t1 frags

    // ---- silu + pack t1 into A2-frag layout (first 16 KB of afrag) ----
#pragma unroll
    for (int nt = 0; nt < 8; ++nt) {
        int n1 = nt * 16 + colb;
        int kc2 = n1 >> 5, hi2 = (n1 >> 3) & 3, j2 = n1 & 7;
#pragma unroll
        for (int r = 0; r < 4; ++r) {
            float t1v = silu_f(acc1[nt][r] + b1[n1]);
            int m2 = quad * 4 + r;
            afrag[(((w * 4 + kc2) * 64) + hi2 * 16 + m2) * 8 + j2] = f2bf_bits(t1v);
        }
    }
    __syncthreads();

    // ---- load A2 frags (own rows) ----
    short8 a2[4];
#pragma unroll
    for (int kc = 0; kc < 4; ++kc)
        a2[kc] = *(const short8*)(&afrag[((w * 4 + kc) * 64 + lane) * 8]);

    // ---- MFMA2 + fused epilogue per channel-group ----
    for (int i = 0; i < 8; ++i) {
        float4v accd = {0.f,0.f,0.f,0.f}, acca = {0.f,0.f,0.f,0.f}, accb = {0.f,0.f,0.f,0.f};
#pragma unroll
        for (int kc = 0; kc < 4; ++kc) {
            short8 bd = *(const short8*)(W2frag + ((size_t)((i      ) * 4 + kc) * 64 + lane) * 8);
            short8 ba = *(const short8*)(W2frag + ((size_t)((8  + i) * 4 + kc) * 64 + lane) * 8);
            short8 bb = *(const short8*)(W2frag + ((size_t)((16 + i) * 4 + kc) * 64 + lane) * 8);
            accd = __builtin_amdgcn_mfma_f32_16x16x32_bf16(a2[kc], bd, accd, 0, 0, 0);
            acca = __builtin_amdgcn_mfma_f32_16x16x32_bf16(a2[kc], ba, acca, 0, 0, 0);
            accb = __builtin_amdgcn_mfma_f32_16x16x32_bf16(a2[kc], bb, accb, 0, 0, 0);
        }
        int c = i * 16 + colb;
        float bdv = b2[c], bav = b2[128 + c], bbv = b2[256 + c];
#pragma unroll
        for (int r = 0; r < 4; ++r) {
            int rr = r0 + 16 * w + quad * 4 + r;
            if (rr < NA) {
                float ds = accd[r] + bdv;
                float al = acca[r] + bav;
                float be = accb[r] + bbv;
                s[(size_t)rr * HD + c] += ds;
                size_t vx = (size_t)rr * 3 * HD + c;
                v[vx]        = tob(al * tof(v[vx])        + be * m_v[vx]);
                v[vx + HD]   = tob(al * tof(v[vx + HD])   + be * m_v[vx + HD]);
                v[vx + 2*HD] = tob(al * tof(v[vx + 2*HD]) + be * m_v[vx + 2*HD]);
            }
        }
    }
}

// ---------------- readout ----------------
__global__ __launch_bounds__(128) void readout_kernel(
    const float* __restrict__ s, const int* __restrict__ batch,
    const float* __restrict__ lamW1, const float* __restrict__ lamb1,
    const float* __restrict__ lamW2, const float* __restrict__ lamb2,
    const float* __restrict__ phiW1, const float* __restrict__ phib1,
    const float* __restrict__ phiW2, const float* __restrict__ phib2,
    float* __restrict__ out)
{
    __shared__ int seg[2];
    __shared__ float hms[HD];
    __shared__ float red[HD];
    int m = blockIdx.x, c = threadIdx.x;
    if (c < 2) {
        int target = m + c;
        int lo = 0, hi = NA;
        while (lo < hi) { int mid = (lo + hi) >> 1; if (batch[mid] < target) lo = mid + 1; else hi = mid; }
        seg[c] = lo;
    }
    __syncthreads();
    int st = seg[0], en = seg[1];
    float acc = 0.f;
    for (int n2 = st; n2 < en; ++n2) acc += s[(size_t)n2 * HD + c];
    float hm = acc / (float)(en - st);
    hms[c] = hm;
    __syncthreads();

    float t = lamb1[c];
    for (int k = 0; k < HD; ++k) t += hms[k] * lamW1[k * HD + c];
    t = silu_f(t);
    red[c] = t * lamW2[c];
    __syncthreads();
    for (int off = 64; off > 0; off >>= 1) { if (c < off) red[c] += red[c + off]; __syncthreads(); }
    if (c == 0) out[m] = red[0] + lamb2[0];
    __syncthreads();

    t = phib1[c];
    for (int k = 0; k < HD; ++k) t += hms[k] * phiW1[k * HD + c];
    t = silu_f(t);
    red[c] = t * phiW2[c];
    __syncthreads();
    for (int off = 64; off > 0; off >>= 1) { if (c < off) red[c] += red[c + off]; __syncthreads(); }
    if (c == 0) { float x = red[0] + phib2[0]; out[NM + m] = 1.0f / (1.0f + __expf(-x)); }
}

// ---------------- host ----------------
extern "C" void kernel_launch(void* const* d_in, const int* in_sizes, int n_in,
                              void* d_out, int out_size, void* d_ws, size_t ws_size,
                              hipStream_t stream) {
    (void)in_sizes; (void)n_in; (void)out_size; (void)ws_size;
    const int*   z          = (const int*)  d_in[0];
    const float* pos        = (const float*)d_in[1];
    const int*   edge_index = (const int*)  d_in[2];
    const int*   batch      = (const int*)  d_in[3];
    const float* emb        = (const float*)d_in[4];
    const float* filt_W1    = (const float*)d_in[5];
    const float* filt_b1    = (const float*)d_in[6];
    const float* filt_W2    = (const float*)d_in[7];
    const float* filt_b2    = (const float*)d_in[8];
    const float* upd_W1     = (const float*)d_in[9];
    const float* upd_b1     = (const float*)d_in[10];
    const float* upd_W2     = (const float*)d_in[11];
    const float* upd_b2     = (const float*)d_in[12];
    const float* lam_W1     = (const float*)d_in[13];
    const float* lam_b1     = (const float*)d_in[14];
    const float* lam_W2     = (const float*)d_in[15];
    const float* lam_b2     = (const float*)d_in[16];
    const float* phi_W1     = (const float*)d_in[17];
    const float* phi_b1     = (const float*)d_in[18];
    const float* phi_W2     = (const float*)d_in[19];
    const float* phi_b2     = (const float*)d_in[20];
    float* out = (float*)d_out;

    const int* row = edge_index;
    const int* col = edge_index + NE;

    char* ws = (char*)d_ws;
    size_t off = 0;
    auto alloc = [&](size_t bytes) -> char* {
        char* p = ws + off;
        off = (off + bytes + 255) & ~(size_t)255;
        return p;
    };
    float* dist_g  = (float*)alloc((size_t)NE * 4);
    float* dirs    = (float*)alloc((size_t)NE * 3 * 4);
    int*   csr_eid = (int*)  alloc((size_t)NE * 4);
    int*   row_ptr = (int*)  alloc((size_t)(NA + 1) * 4);
    int*   deg     = (int*)  alloc((size_t)NA * 4);
    int*   cursor  = (int*)  alloc((size_t)NA * 4);
    float* s       = (float*)alloc((size_t)NA * HD * 4);
    bf16*  v       = (bf16*) alloc((size_t)NA * HD * 3 * 2);
    float* m_s     = (float*)alloc((size_t)NA * HD * 4);
    float* m_v     = (float*)alloc((size_t)NA * HD * 3 * 4);   // f32 planar (atomics)
    // B-frag packs: each family 4 layers x (N/16)*(K/32)*64 items x 8 shorts
    unsigned short* fW2frag = (unsigned short*)alloc((size_t)NL * 24 * 4 * 64 * 8 * 2);
    unsigned short* uW1frag = (unsigned short*)alloc((size_t)NL * 8 * 12 * 64 * 8 * 2);
    unsigned short* uW2frag = (unsigned short*)alloc((size_t)NL * 24 * 4 * 64 * 8 * 2);

    const int EB = (NE + 255) / 256;
    const int NB = (NA * HD) / 256;
    const int MSG_BLOCKS = NE / 64;            // 6250 (exact)
    const int UPD_BLOCKS = (NA + 63) / 64;     // 782

    hipMemsetAsync(deg, 0, (size_t)NA * 4, stream);
    geom_kernel<<<EB, 256, 0, stream>>>(pos, row, col, dist_g, dirs);
    deg_kernel<<<EB, 256, 0, stream>>>(row, deg);
    scan_kernel<<<1, 1024, 0, stream>>>(deg, row_ptr, cursor);
    scatter_kernel<<<EB, 256, 0, stream>>>(row, cursor, csr_eid);
    embed_kernel<<<NB, 256, 0, stream>>>(z, emb, s, v);
    pack_bfrag_kernel<<<96, 256, 0, stream>>>(filt_W2, 128, 384, NL, fW2frag);
    pack_bfrag_kernel<<<96, 256, 0, stream>>>(upd_W1, 384, 128, NL, uW1frag);
    pack_bfrag_kernel<<<96, 256, 0, stream>>>(upd_W2, 128, 384, NL, uW2frag);

    for (int i = 0; i < NL; ++i) {
        const float* fW1 = filt_W1 + (size_t)i * 20 * HD;
        const float* fb1 = filt_b1 + (size_t)i * HD;
        const float* fb2 = filt_b2 + (size_t)i * 384;
        const unsigned short* fW2f = fW2frag + (size_t)i * 24 * 4 * 64 * 8;
        const unsigned short* uW1f = uW1frag + (size_t)i * 8 * 12 * 64 * 8;
        const unsigned short* uW2f = uW2frag + (size_t)i * 24 * 4 * 64 * 8;
        const float* ub1 = upd_b1 + (size_t)i * HD;
        const float* ub2 = upd_b2 + (size_t)i * 384;

        hipMemsetAsync(m_s, 0, (size_t)NA * HD * 4, stream);
        hipMemsetAsync(m_v, 0, (size_t)NA * HD * 3 * 4, stream);
        layer_msg_kernel<<<MSG_BLOCKS, 256, 0, stream>>>(
            dist_g, csr_eid, row_ptr, row, col, dirs,
            fW1, fb1, fW2f, fb2, s, v, m_s, m_v);
        upd12_kernel<<<UPD_BLOCKS, 256, 0, stream>>>(
            s, v, m_s, m_v, uW1f, ub1, uW2f, ub2);
    }

    readout_kernel<<<NM, 128, 0, stream>>>(s, batch,
        lam_W1, lam_b1, lam_W2, lam_b2,
        phi_W1, phi_b1, phi_W2, phi_b2, out);
}

// Round 5
// 1604.588 us; speedup vs baseline: 5.8468x; 1.5536x over previous
//
#include <hip/hip_runtime.h>
#include <hip/hip_bf16.h>

// ---------------- constants (match reference) ----------------
static constexpr int NA = 50000;   // atoms
static constexpr int NE = 400000;  // edges
static constexpr int HD = 128;     // hidden
static constexpr int NL = 4;       // layers
static constexpr int NM = 500;     // molecules
static constexpr int EPB = 32;     // edges per msg block (NE/EPB = 12500 exact)
static constexpr int HS = 400;     // h row stride in shorts (quad-disjoint banks)

typedef __hip_bfloat16 bf16;
typedef short short8 __attribute__((ext_vector_type(8)));
typedef float float4v __attribute__((ext_vector_type(4)));

__device__ __forceinline__ float tof(bf16 x) { return __bfloat162float(x); }
__device__ __forceinline__ bf16  tob(float x) { return __float2bfloat16(x); }
__device__ __forceinline__ unsigned short f2bf_bits(float x) {
    union { float f; unsigned int u; } c; c.f = x;
    unsigned int lsb = (c.u >> 16) & 1u;
    return (unsigned short)((c.u + 0x7fffu + lsb) >> 16);
}
__device__ __forceinline__ float bf2f(unsigned short b) {
    union { unsigned int u; float f; } c; c.u = ((unsigned int)b) << 16;
    return c.f;
}
__device__ __forceinline__ float silu_f(float x) {
    float sg = 1.0f / (1.0f + __expf(-x));
    return x * sg;
}

// ---------------- geometry: dist, dirs ----------------
__global__ void geom_kernel(const float* __restrict__ pos,
                            const int* __restrict__ row, const int* __restrict__ col,
                            float* __restrict__ dist_g, float* __restrict__ dirs) {
    int e = blockIdx.x * 256 + threadIdx.x;
    if (e >= NE) return;
    int r = row[e], c = col[e];
    float dx = pos[c*3+0] - pos[r*3+0];
    float dy = pos[c*3+1] - pos[r*3+1];
    float dz = pos[c*3+2] - pos[r*3+2];
    float dist = sqrtf(dx*dx + dy*dy + dz*dz);
    float inv = 1.0f / (dist + 1e-8f);
    dist_g[e] = dist;
    dirs[e*3+0] = dx*inv; dirs[e*3+1] = dy*inv; dirs[e*3+2] = dz*inv;
}

// ---------------- CSR build ----------------
__global__ void deg_kernel(const int* __restrict__ row, int* __restrict__ deg) {
    int e = blockIdx.x * 256 + threadIdx.x;
    if (e >= NE) return;
    atomicAdd(&deg[row[e]], 1);
}

__global__ __launch_bounds__(1024) void scan_kernel(const int* __restrict__ deg,
                                                    int* __restrict__ row_ptr,
                                                    int* __restrict__ cursor) {
    __shared__ int sh[1024];
    __shared__ int carry_sh;
    int t = threadIdx.x;
    if (t == 0) { carry_sh = 0; row_ptr[0] = 0; }
    __syncthreads();
    for (int base = 0; base < NA; base += 1024) {
        int x = (base + t < NA) ? deg[base + t] : 0;
        sh[t] = x;
        __syncthreads();
        for (int off = 1; off < 1024; off <<= 1) {
            int v_ = (t >= off) ? sh[t - off] : 0;
            __syncthreads();
            sh[t] += v_;
            __syncthreads();
        }
        int incl = sh[t];
        int carry = carry_sh;
        if (base + t < NA) {
            row_ptr[base + t + 1] = carry + incl;
            cursor[base + t] = carry + incl - x;
        }
        __syncthreads();
        if (t == 1023) carry_sh = carry + incl;
        __syncthreads();
    }
}

__global__ void scatter_kernel(const int* __restrict__ row, int* __restrict__ cursor,
                               int* __restrict__ csr_eid) {
    int e = blockIdx.x * 256 + threadIdx.x;
    if (e >= NE) return;
    int p = atomicAdd(&cursor[row[e]], 1);
    csr_eid[p] = e;
}

// ---------------- node init: s = emb[z] (+bf16 mirror), v = 0 (planar) ----------
__global__ void embed_kernel(const int* __restrict__ z, const float* __restrict__ emb,
                             float* __restrict__ s, unsigned short* __restrict__ s_bf,
                             bf16* __restrict__ v) {
    int idx = blockIdx.x * 256 + threadIdx.x;
    if (idx >= NA * HD) return;
    int n = idx >> 7, c = idx & 127;
    float val = emb[z[n] * HD + c];
    s[idx] = val;
    s_bf[idx] = f2bf_bits(val);
    bf16* vb = v + (size_t)n * 3 * HD + c;
    bf16 z16 = tob(0.f);
    vb[0] = z16; vb[HD] = z16; vb[2*HD] = z16;
}

// ---------------- generic weight -> B-fragment-linear bf16 ----------------
__global__ void pack_bfrag_kernel(const float* __restrict__ W, int K, int N,
                                  int layers, unsigned short* __restrict__ out) {
    int NT = N >> 4, KC = K >> 5;
    int total = layers * NT * KC * 64;
    int idx = blockIdx.x * 256 + threadIdx.x;
    if (idx >= total) return;
    int lane = idx & 63;
    int kc = (idx >> 6) % KC;
    int nt = ((idx >> 6) / KC) % NT;
    int layer = (idx >> 6) / (KC * NT);
    const float* Wl = W + (size_t)layer * K * N;
    int n = nt * 16 + (lane & 15);
    int k0 = kc * 32 + (lane >> 4) * 8;
    short8 pk;
#pragma unroll
    for (int j = 0; j < 8; ++j)
        pk[j] = (short)f2bf_bits(Wl[(size_t)(k0 + j) * N + n]);
    *(short8*)(&out[(size_t)idx * 8]) = pk;
}

// ---------------- fused filter + aggregate: 32 CSR edges per block ----------------
__global__ __launch_bounds__(256, 4) void layer_msg_kernel(
    const float* __restrict__ dist_g, const int* __restrict__ csr_eid,
    const int* __restrict__ row_ptr, const int* __restrict__ row,
    const int* __restrict__ col, const float* __restrict__ dirs,
    const float* __restrict__ W1, const float* __restrict__ b1,
    const unsigned short* __restrict__ W2frag, const float* __restrict__ b2,
    const unsigned short* __restrict__ s_bf, const unsigned short* __restrict__ v_bf,
    float* __restrict__ m_s, float* __restrict__ m_v)
{
    // union: phases 1-2: t_frag (8 KB) + w1_s (10 KB @ +8K). phase 3-4: h_l (25.6 KB)
    __shared__ __align__(16) char smem[EPB * HS * 2];
    unsigned short* t_frag = (unsigned short*)smem;
    float* w1_s = (float*)(smem + 8192);
    unsigned short* h_l = (unsigned short*)smem;
    __shared__ float dist_s[EPB];
    __shared__ int   col_s[EPB];
    __shared__ int   rid_s[EPB];
    __shared__ float dirs_s[EPB * 3];

    int tid = threadIdx.x;
    int base = blockIdx.x * EPB;

    if (tid < EPB) {
        int eid = csr_eid[base + tid];
        dist_s[tid] = dist_g[eid];
        col_s[tid] = col[eid];
        rid_s[tid] = row[eid];
        dirs_s[tid*3+0] = dirs[eid*3+0];
        dirs_s[tid*3+1] = dirs[eid*3+1];
        dirs_s[tid*3+2] = dirs[eid*3+2];
    }
    for (int i = tid; i < 20 * HD; i += 256) w1_s[i] = W1[i];
    __syncthreads();

    int lane = tid & 63, w = tid >> 6;

    // ---- phase 1: GEMM1 (VALU). thread: edge = tid&31, channels [cg*16, cg*16+16) ----
    {
        int e = tid & 31, cg = tid >> 5;
        float d = dist_s[e];
        float rk[20];
#pragma unroll
        for (int k = 0; k < 20; ++k) { float t = d - (5.0f/19.0f)*(float)k; rk[k] = __expf(-t*t); }
        float acc[16];
#pragma unroll
        for (int m = 0; m < 16; ++m) acc[m] = b1[cg*16 + m];
#pragma unroll
        for (int k = 0; k < 20; ++k) {
            const float4* wrow = (const float4*)(&w1_s[k * HD + cg * 16]);
            float r = rk[k];
#pragma unroll
            for (int m4 = 0; m4 < 4; ++m4) {
                float4 wv = wrow[m4];
                acc[m4*4+0] += r * wv.x; acc[m4*4+1] += r * wv.y;
                acc[m4*4+2] += r * wv.z; acc[m4*4+3] += r * wv.w;
            }
        }
        int et = e >> 4, m = e & 15, kc = cg >> 1;
#pragma unroll
        for (int h2 = 0; h2 < 2; ++h2) {
            int kq = (cg & 1) * 2 + h2;
            short8 vv;
#pragma unroll
            for (int j = 0; j < 8; ++j)
                vv[j] = (short)f2bf_bits(silu_f(acc[h2*8 + j]));
            int fi = (((et * 4 + kc) * 64) + kq * 16 + m) * 8;
            *(short8*)(&t_frag[fi]) = vv;
        }
    }
    __syncthreads();

    // ---- phase 2: wave w handles edge-half et = w&1, nt-half (w>>1) ----
    int et = w & 1;
    short8 a[4];
#pragma unroll
    for (int kc = 0; kc < 4; ++kc)
        a[kc] = *(const short8*)(&t_frag[((et * 4 + kc) * 64 + lane) * 8]);
    __syncthreads();   // frag reads done -> smem becomes h_l

    // ---- phase 3: MFMA GEMM2, write h (bf16) to LDS ----
    int colb = lane & 15, quad = lane >> 4;
    int ntb = (w >> 1) * 12;
    for (int i = 0; i < 12; ++i) {
        int nt = ntb + i;
        float4v acc = {0.f, 0.f, 0.f, 0.f};
#pragma unroll
        for (int kc = 0; kc < 4; ++kc) {
            short8 b = *(const short8*)(W2frag + ((size_t)(nt * 4 + kc) * 64 + lane) * 8);
            acc = __builtin_amdgcn_mfma_f32_16x16x32_bf16(a[kc], b, acc, 0, 0, 0);
        }
        int n = nt * 16 + colb;
        float bias = b2[n];
#pragma unroll
        for (int r = 0; r < 4; ++r) {
            int e = et * 16 + quad * 4 + r;
            h_l[e * HS + n] = f2bf_bits(acc[r] + bias);
        }
    }
    __syncthreads();

    // ---- phase 4: per-node aggregation, 2 node-parity teams x 128 channels ----
    int c = tid & 127, team = tid >> 7;
    int node_lo = rid_s[0], node_hi = rid_s[EPB - 1];
    for (int n = node_lo + team; n <= node_hi; n += 2) {
        int p0 = row_ptr[n], p1 = row_ptr[n + 1];
        int lo = p0 - base; if (lo < 0) lo = 0;
        int hi = p1 - base; if (hi > EPB) hi = EPB;
        if (lo >= hi) continue;
        bool interior = (p0 >= base) && (p1 <= base + EPB);
        float as = 0.f, av0 = 0.f, av1 = 0.f, av2 = 0.f;
        int e = lo;
        do {
            int eb = (e + 1 < hi) ? e + 1 : e;
            int ci0 = col_s[e], ci1 = col_s[eb];
            // issue all 8 scattered loads before any use
            unsigned short sr0 = s_bf[(size_t)ci0 * HD + c];
            unsigned short v00 = v_bf[(size_t)ci0 * 384 + c];
            unsigned short v01 = v_bf[(size_t)ci0 * 384 + 128 + c];
            unsigned short v02 = v_bf[(size_t)ci0 * 384 + 256 + c];
            unsigned short sr1 = s_bf[(size_t)ci1 * HD + c];
            unsigned short v10 = v_bf[(size_t)ci1 * 384 + c];
            unsigned short v11 = v_bf[(size_t)ci1 * 384 + 128 + c];
            unsigned short v12 = v_bf[(size_t)ci1 * 384 + 256 + c];

            {
                float pss = bf2f(h_l[e * HS + c]);
                float pvv = bf2f(h_l[e * HS + 128 + c]);
                float psv = bf2f(h_l[e * HS + 256 + c]);
                float sc = bf2f(sr0);
                float svd = psv * sc;
                as  += pss * sc;
                av0 += pvv * bf2f(v00) + svd * dirs_s[e*3];
                av1 += pvv * bf2f(v01) + svd * dirs_s[e*3+1];
                av2 += pvv * bf2f(v02) + svd * dirs_s[e*3+2];
            }
            if (eb != e) {
                float pss = bf2f(h_l[eb * HS + c]);
                float pvv = bf2f(h_l[eb * HS + 128 + c]);
                float psv = bf2f(h_l[eb * HS + 256 + c]);
                float sc = bf2f(sr1);
                float svd = psv * sc;
                as  += pss * sc;
                av0 += pvv * bf2f(v10) + svd * dirs_s[eb*3];
                av1 += pvv * bf2f(v11) + svd * dirs_s[eb*3+1];
                av2 += pvv * bf2f(v12) + svd * dirs_s[eb*3+2];
            }
            e += 2;
        } while (e < hi);
        size_t ms_ix = (size_t)n * HD + c;
        size_t mv_ix = (size_t)n * 3 * HD + c;
        if (interior) {
            m_s[ms_ix] = as;
            m_v[mv_ix] = av0; m_v[mv_ix + HD] = av1; m_v[mv_ix + 2*HD] = av2;
        } else {
            atomicAdd(&m_s[ms_ix], as);
            atomicAdd(&m_v[mv_ix], av0);
            atomicAdd(&m_v[mv_ix + HD], av1);
            atomicAdd(&m_v[mv_ix + 2*HD], av2);
        }
    }
}

// ---------------- fused update MLP (MFMA x2) + s/v apply: 64 atoms per block -------
__global__ __launch_bounds__(256) void upd12_kernel(
    float* __restrict__ s, unsigned short* __restrict__ s_bf, bf16* __restrict__ v,
    const float* __restrict__ m_s, const float* __restrict__ m_v,
    const unsigned short* __restrict__ W1frag, const float* __restrict__ b1,
    const unsigned short* __restrict__ W2frag, const float* __restrict__ b2)
{
    __shared__ __align__(16) unsigned short afrag[64 * 384];
    int tid = threadIdx.x;
    int r0 = blockIdx.x * 64;

#pragma unroll
    for (int t = 0; t < 12; ++t) {
        int id = tid + 256 * t;
        int r = id / 48;
        int kg = id % 48;
        int rr = r0 + r; if (rr >= NA) rr = NA - 1;
        float vals[8];
        if (kg < 16) {
            const float* p = s + (size_t)rr * HD + kg * 8;
#pragma unroll
            for (int j = 0; j < 8; ++j) vals[j] = p[j];
        } else if (kg < 32) {
            const float* p = m_s + (size_t)rr * HD + (kg - 16) * 8;
#pragma unroll
            for (int j = 0; j < 8; ++j) vals[j] = p[j];
        } else {
            int cb = (kg - 32) * 8;
            const float* p = m_v + (size_t)rr * 3 * HD + cb;
#pragma unroll
            for (int j = 0; j < 8; ++j) {
                float x = p[j], y = p[HD + j], z = p[2*HD + j];
                vals[j] = sqrtf(x*x + y*y + z*z);
            }
        }
        int kc = kg >> 2, hi = kg & 3, m = r & 15, rt = r >> 4;
        short8 pk;
#pragma unroll
        for (int j = 0; j < 8; ++j) pk[j] = (short)f2bf_bits(vals[j]);
        *(short8*)(&afrag[(((rt * 12 + kc) * 64) + hi * 16 + m) * 8]) = pk;
    }
    __syncthreads();

    int lane = tid & 63, w = tid >> 6;
    int colb = lane & 15, quad = lane >> 4;

    float4v acc1[8];
#pragma unroll
    for (int nt = 0; nt < 8; ++nt) acc1[nt] = (float4v){0.f,0.f,0.f,0.f};
    for (int kc = 0; kc < 12; ++kc) {
        short8 a = *(const short8*)(&afrag[((w * 12 + kc) * 64 + lane) * 8]);
#pragma unroll
        for (int nt = 0; nt < 8; ++nt) {
            short8 b = *(const short8*)(W1frag + ((size_t)(nt * 12 + kc) * 64 + lane) * 8);
            acc1[nt] = __builtin_amdgcn_mfma_f32_16x16x32_bf16(a, b, acc1[nt], 0, 0, 0);
        }
    }
    __syncthreads();

#pragma unroll
    for (int nt = 0; nt < 8; ++nt) {
        int n1 = nt * 16 + colb;
        int kc2 = n1 >> 5, hi2 = (n1 >> 3) & 3, j2 = n1 & 7;
#pragma unroll
        for (int r = 0; r < 4; ++r) {
            float t1v = silu_f(acc1[nt][r] + b1[n1]);
            int m2 = quad * 4 + r;
            afrag[(((w * 4 + kc2) * 64) + hi2 * 16 + m2) * 8 + j2] = f2bf_bits(t1v);
        }
    }
    __syncthreads();

    short8 a2[4];
#pragma unroll
    for (int kc = 0; kc < 4; ++kc)
        a2[kc] = *(const short8*)(&afrag[((w * 4 + kc) * 64 + lane) * 8]);

    for (int i = 0; i < 8; ++i) {
        float4v accd = {0.f,0.f,0.f,0.f}, acca = {0.f,0.f,0.f,0.f}, accb = {0.f,0.f,0.f,0.f};
#pragma unroll
        for (int kc = 0; kc < 4; ++kc) {
            short8 bd = *(const short8*)(W2frag + ((size_t)((i      ) * 4 + kc) * 64 + lane) * 8);
            short8 ba = *(const short8*)(W2frag + ((size_t)((8  + i) * 4 + kc) * 64 + lane) * 8);
            short8 bb = *(const short8*)(W2frag + ((size_t)((16 + i) * 4 + kc) * 64 + lane) * 8);
            accd = __builtin_amdgcn_mfma_f32_16x16x32_bf16(a2[kc], bd, accd, 0, 0, 0);
            acca = __builtin_amdgcn_mfma_f32_16x16x32_bf16(a2[kc], ba, acca, 0, 0, 0);
            accb = __builtin_amdgcn_mfma_f32_16x16x32_bf16(a2[kc], bb, accb, 0, 0, 0);
        }
        int c = i * 16 + colb;
        float bdv = b2[c], bav = b2[128 + c], bbv = b2[256 + c];
#pragma unroll
        for (int r = 0; r < 4; ++r) {
            int rr = r0 + 16 * w + quad * 4 + r;
            if (rr < NA) {
                float ds = accd[r] + bdv;
                float al = acca[r] + bav;
                float be = accb[r] + bbv;
                size_t sx = (size_t)rr * HD + c;
                float news = s[sx] + ds;
                s[sx] = news;
                s_bf[sx] = f2bf_bits(news);
                size_t vx = (size_t)rr * 3 * HD + c;
                v[vx]        = tob(al * tof(v[vx])        + be * m_v[vx]);
                v[vx + HD]   = tob(al * tof(v[vx + HD])   + be * m_v[vx + HD]);
                v[vx + 2*HD] = tob(al * tof(v[vx + 2*HD]) + be * m_v[vx + 2*HD]);
            }
        }
    }
}

// ---------------- readout ----------------
__global__ __launch_bounds__(128) void readout_kernel(
    const float* __restrict__ s, const int* __restrict__ batch,
    const float* __restrict__ lamW1, const float* __restrict__ lamb1,
    const float* __restrict__ lamW2, const float* __restrict__ lamb2,
    const float* __restrict__ phiW1, const float* __restrict__ phib1,
    const float* __restrict__ phiW2, const float* __restrict__ phib2,
    float* __restrict__ out)
{
    __shared__ int seg[2];
    __shared__ float hms[HD];
    __shared__ float red[HD];
    int m = blockIdx.x, c = threadIdx.x;
    if (c < 2) {
        int target = m + c;
        int lo = 0, hi = NA;
        while (lo < hi) { int mid = (lo + hi) >> 1; if (batch[mid] < target) lo = mid + 1; else hi = mid; }
        seg[c] = lo;
    }
    __syncthreads();
    int st = seg[0], en = seg[1];
    float acc = 0.f;
    for (int n2 = st; n2 < en; ++n2) acc += s[(size_t)n2 * HD + c];
    float hm = acc / (float)(en - st);
    hms[c] = hm;
    __syncthreads();

    float t = lamb1[c];
    for (int k = 0; k < HD; ++k) t += hms[k] * lamW1[k * HD + c];
    t = silu_f(t);
    red[c] = t * lamW2[c];
    __syncthreads();
    for (int off = 64; off > 0; off >>= 1) { if (c < off) red[c] += red[c + off]; __syncthreads(); }
    if (c == 0) out[m] = red[0] + lamb2[0];
    __syncthreads();

    t = phib1[c];
    for (int k = 0; k < HD; ++k) t += hms[k] * phiW1[k * HD + c];
    t = silu_f(t);
    red[c] = t * phiW2[c];
    __syncthreads();
    for (int off = 64; off > 0; off >>= 1) { if (c < off) red[c] += red[c + off]; __syncthreads(); }
    if (c == 0) { float x = red[0] + phib2[0]; out[NM + m] = 1.0f / (1.0f + __expf(-x)); }
}

// ---------------- host ----------------
extern "C" void kernel_launch(void* const* d_in, const int* in_sizes, int n_in,
                              void* d_out, int out_size, void* d_ws, size_t ws_size,
                              hipStream_t stream) {
    (void)in_sizes; (void)n_in; (void)out_size; (void)ws_size;
    const int*   z          = (const int*)  d_in[0];
    const float* pos        = (const float*)d_in[1];
    const int*   edge_index = (const int*)  d_in[2];
    const int*   batch      = (const int*)  d_in[3];
    const float* emb        = (const float*)d_in[4];
    const float* filt_W1    = (const float*)d_in[5];
    const float* filt_b1    = (const float*)d_in[6];
    const float* filt_W2    = (const float*)d_in[7];
    const float* filt_b2    = (const float*)d_in[8];
    const float* upd_W1     = (const float*)d_in[9];
    const float* upd_b1     = (const float*)d_in[10];
    const float* upd_W2     = (const float*)d_in[11];
    const float* upd_b2     = (const float*)d_in[12];
    const float* lam_W1     = (const float*)d_in[13];
    const float* lam_b1     = (const float*)d_in[14];
    const float* lam_W2     = (const float*)d_in[15];
    const float* lam_b2     = (const float*)d_in[16];
    const float* phi_W1     = (const float*)d_in[17];
    const float* phi_b1     = (const float*)d_in[18];
    const float* phi_W2     = (const float*)d_in[19];
    const float* phi_b2     = (const float*)d_in[20];
    float* out = (float*)d_out;

    const int* row = edge_index;
    const int* col = edge_index + NE;

    char* ws = (char*)d_ws;
    size_t off = 0;
    auto alloc = [&](size_t bytes) -> char* {
        char* p = ws + off;
        off = (off + bytes + 255) & ~(size_t)255;
        return p;
    };
    float* dist_g  = (float*)alloc((size_t)NE * 4);
    float* dirs    = (float*)alloc((size_t)NE * 3 * 4);
    int*   csr_eid = (int*)  alloc((size_t)NE * 4);
    int*   row_ptr = (int*)  alloc((size_t)(NA + 1) * 4);
    int*   deg     = (int*)  alloc((size_t)NA * 4);
    int*   cursor  = (int*)  alloc((size_t)NA * 4);
    float* s       = (float*)alloc((size_t)NA * HD * 4);
    unsigned short* s_bf = (unsigned short*)alloc((size_t)NA * HD * 2);
    bf16*  v       = (bf16*) alloc((size_t)NA * HD * 3 * 2);
    float* m_s     = (float*)alloc((size_t)NA * HD * 4);
    float* m_v     = (float*)alloc((size_t)NA * HD * 3 * 4);
    unsigned short* fW2frag = (unsigned short*)alloc((size_t)NL * 24 * 4 * 64 * 8 * 2);
    unsigned short* uW1frag = (unsigned short*)alloc((size_t)NL * 8 * 12 * 64 * 8 * 2);
    unsigned short* uW2frag = (unsigned short*)alloc((size_t)NL * 24 * 4 * 64 * 8 * 2);

    const int EB = (NE + 255) / 256;
    const int NB = (NA * HD) / 256;
    const int MSG_BLOCKS = NE / EPB;           // 12500 (exact)
    const int UPD_BLOCKS = (NA + 63) / 64;     // 782

    hipMemsetAsync(deg, 0, (size_t)NA * 4, stream);
    geom_kernel<<<EB, 256, 0, stream>>>(pos, row, col, dist_g, dirs);
    deg_kernel<<<EB, 256, 0, stream>>>(row, deg);
    scan_kernel<<<1, 1024, 0, stream>>>(deg, row_ptr, cursor);
    scatter_kernel<<<EB, 256, 0, stream>>>(row, cursor, csr_eid);
    embed_kernel<<<NB, 256, 0, stream>>>(z, emb, s, s_bf, v);
    pack_bfrag_kernel<<<96, 256, 0, stream>>>(filt_W2, 128, 384, NL, fW2frag);
    pack_bfrag_kernel<<<96, 256, 0, stream>>>(upd_W1, 384, 128, NL, uW1frag);
    pack_bfrag_kernel<<<96, 256, 0, stream>>>(upd_W2, 128, 384, NL, uW2frag);

    for (int i = 0; i < NL; ++i) {
        const float* fW1 = filt_W1 + (size_t)i * 20 * HD;
        const float* fb1 = filt_b1 + (size_t)i * HD;
        const float* fb2 = filt_b2 + (size_t)i * 384;
        const unsigned short* fW2f = fW2frag + (size_t)i * 24 * 4 * 64 * 8;
        const unsigned short* uW1f = uW1frag + (size_t)i * 8 * 12 * 64 * 8;
        const unsigned short* uW2f = uW2frag + (size_t)i * 24 * 4 * 64 * 8;
        const float* ub1 = upd_b1 + (size_t)i * HD;
        const float* ub2 = upd_b2 + (size_t)i * 384;

        hipMemsetAsync(m_s, 0, (size_t)NA * HD * 4, stream);
        hipMemsetAsync(m_v, 0, (size_t)NA * HD * 3 * 4, stream);
        layer_msg_kernel<<<MSG_BLOCKS, 256, 0, stream>>>(
            dist_g, csr_eid, row_ptr, row, col, dirs,
            fW1, fb1, fW2f, fb2, s_bf, (const unsigned short*)v, m_s, m_v);
        upd12_kernel<<<UPD_BLOCKS, 256, 0, stream>>>(
            s, s_bf, v, m_s, m_v, uW1f, ub1, uW2f, ub2);
    }

    readout_kernel<<<NM, 128, 0, stream>>>(s, batch,
        lam_W1, lam_b1, lam_W2, lam_b2,
        phi_W1, phi_b1, phi_W2, phi_b2, out);
}

// Round 6
// 1491.215 us; speedup vs baseline: 6.2913x; 1.0760x over previous
//
#include <hip/hip_runtime.h>
#include <hip/hip_bf16.h>

// ---------------- constants (match reference) ----------------
static constexpr int NA = 50000;   // atoms
static constexpr int NE = 400000;  // edges
static constexpr int HD = 128;     // hidden
static constexpr int NL = 4;       // layers
static constexpr int NM = 500;     // molecules
static constexpr int EPB = 32;     // edges per msg block (NE/EPB = 12500 exact)
static constexpr int HS = 404;     // h row stride in shorts (quad-disjoint banks)

typedef __hip_bfloat16 bf16;
typedef short short8 __attribute__((ext_vector_type(8)));
typedef float float4v __attribute__((ext_vector_type(4)));

__device__ __forceinline__ float tof(bf16 x) { return __bfloat162float(x); }
__device__ __forceinline__ bf16  tob(float x) { return __float2bfloat16(x); }
__device__ __forceinline__ unsigned short f2bf_bits(float x) {
    union { float f; unsigned int u; } c; c.f = x;
    unsigned int lsb = (c.u >> 16) & 1u;
    return (unsigned short)((c.u + 0x7fffu + lsb) >> 16);
}
__device__ __forceinline__ float bf2f(unsigned short b) {
    union { unsigned int u; float f; } c; c.u = ((unsigned int)b) << 16;
    return c.f;
}
__device__ __forceinline__ float silu_f(float x) {
    float sg = 1.0f / (1.0f + __expf(-x));
    return x * sg;
}

// ---------------- geometry: dist, dirs ----------------
__global__ void geom_kernel(const float* __restrict__ pos,
                            const int* __restrict__ row, const int* __restrict__ col,
                            float* __restrict__ dist_g, float* __restrict__ dirs) {
    int e = blockIdx.x * 256 + threadIdx.x;
    if (e >= NE) return;
    int r = row[e], c = col[e];
    float dx = pos[c*3+0] - pos[r*3+0];
    float dy = pos[c*3+1] - pos[r*3+1];
    float dz = pos[c*3+2] - pos[r*3+2];
    float dist = sqrtf(dx*dx + dy*dy + dz*dz);
    float inv = 1.0f / (dist + 1e-8f);
    dist_g[e] = dist;
    dirs[e*3+0] = dx*inv; dirs[e*3+1] = dy*inv; dirs[e*3+2] = dz*inv;
}

// ---------------- CSR build ----------------
__global__ void deg_kernel(const int* __restrict__ row, int* __restrict__ deg) {
    int e = blockIdx.x * 256 + threadIdx.x;
    if (e >= NE) return;
    atomicAdd(&deg[row[e]], 1);
}

__global__ __launch_bounds__(1024) void scan_kernel(const int* __restrict__ deg,
                                                    int* __restrict__ row_ptr,
                                                    int* __restrict__ cursor) {
    __shared__ int sh[1024];
    __shared__ int carry_sh;
    int t = threadIdx.x;
    if (t == 0) { carry_sh = 0; row_ptr[0] = 0; }
    __syncthreads();
    for (int base = 0; base < NA; base += 1024) {
        int x = (base + t < NA) ? deg[base + t] : 0;
        sh[t] = x;
        __syncthreads();
        for (int off = 1; off < 1024; off <<= 1) {
            int v_ = (t >= off) ? sh[t - off] : 0;
            __syncthreads();
            sh[t] += v_;
            __syncthreads();
        }
        int incl = sh[t];
        int carry = carry_sh;
        if (base + t < NA) {
            row_ptr[base + t + 1] = carry + incl;
            cursor[base + t] = carry + incl - x;
        }
        __syncthreads();
        if (t == 1023) carry_sh = carry + incl;
        __syncthreads();
    }
}

__global__ void scatter_kernel(const int* __restrict__ row, int* __restrict__ cursor,
                               int* __restrict__ csr_eid) {
    int e = blockIdx.x * 256 + threadIdx.x;
    if (e >= NE) return;
    int p = atomicAdd(&cursor[row[e]], 1);
    csr_eid[p] = e;
}

// ---------------- node init: s = emb[z]; vpack = (s_bf, 0, 0, 0) ----------------
__global__ void embed_kernel(const int* __restrict__ z, const float* __restrict__ emb,
                             float* __restrict__ s, ushort4* __restrict__ vpack) {
    int idx = blockIdx.x * 256 + threadIdx.x;
    if (idx >= NA * HD) return;
    int n = idx >> 7;
    int c = idx & 127;
    float val = emb[z[n] * HD + c];
    s[idx] = val;
    ushort4 q; q.x = f2bf_bits(val); q.y = 0; q.z = 0; q.w = 0;
    vpack[idx] = q;
}

// ---------------- generic weight -> B-fragment-linear bf16 ----------------
__global__ void pack_bfrag_kernel(const float* __restrict__ W, int K, int N,
                                  int layers, unsigned short* __restrict__ out) {
    int NT = N >> 4, KC = K >> 5;
    int total = layers * NT * KC * 64;
    int idx = blockIdx.x * 256 + threadIdx.x;
    if (idx >= total) return;
    int lane = idx & 63;
    int kc = (idx >> 6) % KC;
    int nt = ((idx >> 6) / KC) % NT;
    int layer = (idx >> 6) / (KC * NT);
    const float* Wl = W + (size_t)layer * K * N;
    int n = nt * 16 + (lane & 15);
    int k0 = kc * 32 + (lane >> 4) * 8;
    short8 pk;
#pragma unroll
    for (int j = 0; j < 8; ++j)
        pk[j] = (short)f2bf_bits(Wl[(size_t)(k0 + j) * N + n]);
    *(short8*)(&out[(size_t)idx * 8]) = pk;
}

// ---------------- fused filter + aggregate: 32 CSR edges per block ----------------
__global__ __launch_bounds__(256, 6) void layer_msg_kernel(
    const float* __restrict__ dist_g, const int* __restrict__ csr_eid,
    const int* __restrict__ row_ptr, const int* __restrict__ row,
    const int* __restrict__ col, const float* __restrict__ dirs,
    const float* __restrict__ W1, const float* __restrict__ b1,
    const unsigned short* __restrict__ W2frag, const float* __restrict__ b2,
    const ushort4* __restrict__ vpack,
    float* __restrict__ m_s, float* __restrict__ m_v)
{
    // union: phases 1-2: t_frag (8 KB) + w1_s (10 KB @ +8K). phases 3-4: h_l (25.9 KB)
    __shared__ __align__(16) char smem[EPB * HS * 2];
    unsigned short* t_frag = (unsigned short*)smem;
    float* w1_s = (float*)(smem + 8192);
    unsigned short* h_l = (unsigned short*)smem;
    __shared__ float dist_s[EPB];
    __shared__ int   col_s[EPB];
    __shared__ int   rid_s[EPB];
    __shared__ float dirs_s[EPB * 3];

    int tid = threadIdx.x;
    int base = blockIdx.x * EPB;

    if (tid < EPB) {
        int eid = csr_eid[base + tid];
        dist_s[tid] = dist_g[eid];
        col_s[tid] = col[eid];
        rid_s[tid] = row[eid];
        dirs_s[tid*3+0] = dirs[eid*3+0];
        dirs_s[tid*3+1] = dirs[eid*3+1];
        dirs_s[tid*3+2] = dirs[eid*3+2];
    }
    for (int i = tid; i < 20 * HD; i += 256) w1_s[i] = W1[i];
    __syncthreads();

    int lane = tid & 63, w = tid >> 6;

    // ---- phase 1: GEMM1 (VALU). thread: edge = tid&31, channels [cg*16, cg*16+16) ----
    {
        int e = tid & 31, cg = tid >> 5;
        float d = dist_s[e];
        float rk[20];
#pragma unroll
        for (int k = 0; k < 20; ++k) { float t = d - (5.0f/19.0f)*(float)k; rk[k] = __expf(-t*t); }
        float acc[16];
#pragma unroll
        for (int m = 0; m < 16; ++m) acc[m] = b1[cg*16 + m];
#pragma unroll
        for (int k = 0; k < 20; ++k) {
            const float4* wrow = (const float4*)(&w1_s[k * HD + cg * 16]);
            float r = rk[k];
#pragma unroll
            for (int m4 = 0; m4 < 4; ++m4) {
                float4 wv = wrow[m4];
                acc[m4*4+0] += r * wv.x; acc[m4*4+1] += r * wv.y;
                acc[m4*4+2] += r * wv.z; acc[m4*4+3] += r * wv.w;
            }
        }
        int et = e >> 4, m = e & 15, kc = cg >> 1;
#pragma unroll
        for (int h2 = 0; h2 < 2; ++h2) {
            int kq = (cg & 1) * 2 + h2;
            short8 vv;
#pragma unroll
            for (int j = 0; j < 8; ++j)
                vv[j] = (short)f2bf_bits(silu_f(acc[h2*8 + j]));
            int fi = (((et * 4 + kc) * 64) + kq * 16 + m) * 8;
            *(short8*)(&t_frag[fi]) = vv;
        }
    }
    __syncthreads();

    // ---- phase 2: wave w handles edge-half et = w&1, nt-half (w>>1) ----
    int et = w & 1;
    short8 a[4];
#pragma unroll
    for (int kc = 0; kc < 4; ++kc)
        a[kc] = *(const short8*)(&t_frag[((et * 4 + kc) * 64 + lane) * 8]);
    __syncthreads();   // frag reads done -> smem becomes h_l

    // ---- phase 3: MFMA GEMM2, write h (bf16) to LDS ----
    int colb = lane & 15, quad = lane >> 4;
    int ntb = (w >> 1) * 12;
    for (int i = 0; i < 12; ++i) {
        int nt = ntb + i;
        float4v acc = {0.f, 0.f, 0.f, 0.f};
#pragma unroll
        for (int kc = 0; kc < 4; ++kc) {
            short8 b = *(const short8*)(W2frag + ((size_t)(nt * 4 + kc) * 64 + lane) * 8);
            acc = __builtin_amdgcn_mfma_f32_16x16x32_bf16(a[kc], b, acc, 0, 0, 0);
        }
        int n = nt * 16 + colb;
        float bias = b2[n];
#pragma unroll
        for (int r = 0; r < 4; ++r) {
            int e = et * 16 + quad * 4 + r;
            h_l[e * HS + n] = f2bf_bits(acc[r] + bias);
        }
    }
    __syncthreads();

    // ---- phase 4: per-node aggregation, 2 node-parity teams x 128 channels ----
    int c = tid & 127, team = tid >> 7;
    int node_lo = rid_s[0], node_hi = rid_s[EPB - 1];
    for (int n = node_lo + team; n <= node_hi; n += 2) {
        int p0 = row_ptr[n], p1 = row_ptr[n + 1];
        int lo = p0 - base; if (lo < 0) lo = 0;
        int hi = p1 - base; if (hi > EPB) hi = EPB;
        if (lo >= hi) continue;
        bool interior = (p0 >= base) && (p1 <= base + EPB);
        float as = 0.f, av0 = 0.f, av1 = 0.f, av2 = 0.f;
        int e = lo;
        // unroll-4: 4 outstanding 8B gathers
        for (; e + 4 <= hi; e += 4) {
            ushort4 q0 = vpack[(size_t)col_s[e+0] * HD + c];
            ushort4 q1 = vpack[(size_t)col_s[e+1] * HD + c];
            ushort4 q2 = vpack[(size_t)col_s[e+2] * HD + c];
            ushort4 q3 = vpack[(size_t)col_s[e+3] * HD + c];
#pragma unroll
            for (int j = 0; j < 4; ++j) {
                ushort4 q = (j == 0) ? q0 : (j == 1) ? q1 : (j == 2) ? q2 : q3;
                int ee = e + j;
                float pss = bf2f(h_l[ee * HS + c]);
                float pvv = bf2f(h_l[ee * HS + 128 + c]);
                float psv = bf2f(h_l[ee * HS + 256 + c]);
                float sc = bf2f(q.x);
                float svd = psv * sc;
                as  += pss * sc;
                av0 += pvv * bf2f(q.y) + svd * dirs_s[ee*3];
                av1 += pvv * bf2f(q.z) + svd * dirs_s[ee*3+1];
                av2 += pvv * bf2f(q.w) + svd * dirs_s[ee*3+2];
            }
        }
        for (; e < hi; ++e) {
            ushort4 q = vpack[(size_t)col_s[e] * HD + c];
            float pss = bf2f(h_l[e * HS + c]);
            float pvv = bf2f(h_l[e * HS + 128 + c]);
            float psv = bf2f(h_l[e * HS + 256 + c]);
            float sc = bf2f(q.x);
            float svd = psv * sc;
            as  += pss * sc;
            av0 += pvv * bf2f(q.y) + svd * dirs_s[e*3];
            av1 += pvv * bf2f(q.z) + svd * dirs_s[e*3+1];
            av2 += pvv * bf2f(q.w) + svd * dirs_s[e*3+2];
        }
        size_t ms_ix = (size_t)n * HD + c;
        size_t mv_ix = (size_t)n * 3 * HD + c;
        if (interior) {
            m_s[ms_ix] = as;
            m_v[mv_ix] = av0; m_v[mv_ix + HD] = av1; m_v[mv_ix + 2*HD] = av2;
        } else {
            atomicAdd(&m_s[ms_ix], as);
            atomicAdd(&m_v[mv_ix], av0);
            atomicAdd(&m_v[mv_ix + HD], av1);
            atomicAdd(&m_v[mv_ix + 2*HD], av2);
        }
    }
}

// ---------------- fused update MLP (MFMA x2) + s/v apply + m zeroing -------------
__global__ __launch_bounds__(256) void upd12_kernel(
    float* __restrict__ s, ushort4* __restrict__ vpack,
    float* __restrict__ m_s, float* __restrict__ m_v,
    const unsigned short* __restrict__ W1frag, const float* __restrict__ b1,
    const unsigned short* __restrict__ W2frag, const float* __restrict__ b2)
{
    __shared__ __align__(16) unsigned short afrag[64 * 384];
    int tid = threadIdx.x;
    int r0 = blockIdx.x * 64;

#pragma unroll
    for (int t = 0; t < 12; ++t) {
        int id = tid + 256 * t;
        int r = id / 48;
        int kg = id % 48;
        int rr = r0 + r; if (rr >= NA) rr = NA - 1;
        float vals[8];
        if (kg < 16) {
            const float* p = s + (size_t)rr * HD + kg * 8;
#pragma unroll
            for (int j = 0; j < 8; ++j) vals[j] = p[j];
        } else if (kg < 32) {
            const float* p = m_s + (size_t)rr * HD + (kg - 16) * 8;
#pragma unroll
            for (int j = 0; j < 8; ++j) vals[j] = p[j];
        } else {
            int cb = (kg - 32) * 8;
            const float* p = m_v + (size_t)rr * 3 * HD + cb;
#pragma unroll
            for (int j = 0; j < 8; ++j) {
                float x = p[j], y = p[HD + j], z = p[2*HD + j];
                vals[j] = sqrtf(x*x + y*y + z*z);
            }
        }
        int kc = kg >> 2, hi = kg & 3, m = r & 15, rt = r >> 4;
        short8 pk;
#pragma unroll
        for (int j = 0; j < 8; ++j) pk[j] = (short)f2bf_bits(vals[j]);
        *(short8*)(&afrag[(((rt * 12 + kc) * 64) + hi * 16 + m) * 8]) = pk;
    }
    __syncthreads();

    int lane = tid & 63, w = tid >> 6;
    int colb = lane & 15, quad = lane >> 4;

    float4v acc1[8];
#pragma unroll
    for (int nt = 0; nt < 8; ++nt) acc1[nt] = (float4v){0.f,0.f,0.f,0.f};
    for (int kc = 0; kc < 12; ++kc) {
        short8 a = *(const short8*)(&afrag[((w * 12 + kc) * 64 + lane) * 8]);
#pragma unroll
        for (int nt = 0; nt < 8; ++nt) {
            short8 b = *(const short8*)(W1frag + ((size_t)(nt * 12 + kc) * 64 + lane) * 8);
            acc1[nt] = __builtin_amdgcn_mfma_f32_16x16x32_bf16(a, b, acc1[nt], 0, 0, 0);
        }
    }
    __syncthreads();

#pragma unroll
    for (int nt = 0; nt < 8; ++nt) {
        int n1 = nt * 16 + colb;
        int kc2 = n1 >> 5, hi2 = (n1 >> 3) & 3, j2 = n1 & 7;
#pragma unroll
        for (int r = 0; r < 4; ++r) {
            float t1v = silu_f(acc1[nt][r] + b1[n1]);
            int m2 = quad * 4 + r;
            afrag[(((w * 4 + kc2) * 64) + hi2 * 16 + m2) * 8 + j2] = f2bf_bits(t1v);
        }
    }
    __syncthreads();

    short8 a2[4];
#pragma unroll
    for (int kc = 0; kc < 4; ++kc)
        a2[kc] = *(const short8*)(&afrag[((w * 4 + kc) * 64 + lane) * 8]);

    for (int i = 0; i < 8; ++i) {
        float4v accd = {0.f,0.f,0.f,0.f}, acca = {0.f,0.f,0.f,0.f}, accb = {0.f,0.f,0.f,0.f};
#pragma unroll
        for (int kc = 0; kc < 4; ++kc) {
            short8 bd = *(const short8*)(W2frag + ((size_t)((i      ) * 4 + kc) * 64 + lane) * 8);
            short8 ba = *(const short8*)(W2frag + ((size_t)((8  + i) * 4 + kc) * 64 + lane) * 8);
            short8 bb = *(const short8*)(W2frag + ((size_t)((16 + i) * 4 + kc) * 64 + lane) * 8);
            accd = __builtin_amdgcn_mfma_f32_16x16x32_bf16(a2[kc], bd, accd, 0, 0, 0);
            acca = __builtin_amdgcn_mfma_f32_16x16x32_bf16(a2[kc], ba, acca, 0, 0, 0);
            accb = __builtin_amdgcn_mfma_f32_16x16x32_bf16(a2[kc], bb, accb, 0, 0, 0);
        }
        int c = i * 16 + colb;
        float bdv = b2[c], bav = b2[128 + c], bbv = b2[256 + c];
#pragma unroll
        for (int r = 0; r < 4; ++r) {
            int rr = r0 + 16 * w + quad * 4 + r;
            if (rr < NA) {
                float ds = accd[r] + bdv;
                float al = acca[r] + bav;
                float be = accb[r] + bbv;
                size_t sx = (size_t)rr * HD + c;
                size_t vx = (size_t)rr * 3 * HD + c;
                float news = s[sx] + ds;
                s[sx] = news;
                ushort4 q = vpack[sx];
                float nv0 = al * bf2f(q.y) + be * m_v[vx];
                float nv1 = al * bf2f(q.z) + be * m_v[vx + HD];
                float nv2 = al * bf2f(q.w) + be * m_v[vx + 2*HD];
                ushort4 nq;
                nq.x = f2bf_bits(news);
                nq.y = f2bf_bits(nv0); nq.z = f2bf_bits(nv1); nq.w = f2bf_bits(nv2);
                vpack[sx] = nq;
                // zero m-buffers for the next layer (this block owns these rows)
                m_s[sx] = 0.f;
                m_v[vx] = 0.f; m_v[vx + HD] = 0.f; m_v[vx + 2*HD] = 0.f;
            }
        }
    }
}

// ---------------- readout ----------------
__global__ __launch_bounds__(128) void readout_kernel(
    const float* __restrict__ s, const int* __restrict__ batch,
    const float* __restrict__ lamW1, const float* __restrict__ lamb1,
    const float* __restrict__ lamW2, const float* __restrict__ lamb2,
    const float* __restrict__ phiW1, const float* __restrict__ phib1,
    const float* __restrict__ phiW2, const float* __restrict__ phib2,
    float* __restrict__ out)
{
    __shared__ int seg[2];
    __shared__ float hms[HD];
    __shared__ float red[HD];
    int m = blockIdx.x, c = threadIdx.x;
    if (c < 2) {
        int target = m + c;
        int lo = 0, hi = NA;
        while (lo < hi) { int mid = (lo + hi) >> 1; if (batch[mid] < target) lo = mid + 1; else hi = mid; }
        seg[c] = lo;
    }
    __syncthreads();
    int st = seg[0], en = seg[1];
    float acc = 0.f;
    for (int n2 = st; n2 < en; ++n2) acc += s[(size_t)n2 * HD + c];
    float hm = acc / (float)(en - st);
    hms[c] = hm;
    __syncthreads();

    float t = lamb1[c];
    for (int k = 0; k < HD; ++k) t += hms[k] * lamW1[k * HD + c];
    t = silu_f(t);
    red[c] = t * lamW2[c];
    __syncthreads();
    for (int off = 64; off > 0; off >>= 1) { if (c < off) red[c] += red[c + off]; __syncthreads(); }
    if (c == 0) out[m] = red[0] + lamb2[0];
    __syncthreads();

    t = phib1[c];
    for (int k = 0; k < HD; ++k) t += hms[k] * phiW1[k * HD + c];
    t = silu_f(t);
    red[c] = t * phiW2[c];
    __syncthreads();
    for (int off = 64; off > 0; off >>= 1) { if (c < off) red[c] += red[c + off]; __syncthreads(); }
    if (c == 0) { float x = red[0] + phib2[0]; out[NM + m] = 1.0f / (1.0f + __expf(-x)); }
}

// ---------------- host ----------------
extern "C" void kernel_launch(void* const* d_in, const int* in_sizes, int n_in,
                              void* d_out, int out_size, void* d_ws, size_t ws_size,
                              hipStream_t stream) {
    (void)in_sizes; (void)n_in; (void)out_size; (void)ws_size;
    const int*   z          = (const int*)  d_in[0];
    const float* pos        = (const float*)d_in[1];
    const int*   edge_index = (const int*)  d_in[2];
    const int*   batch      = (const int*)  d_in[3];
    const float* emb        = (const float*)d_in[4];
    const float* filt_W1    = (const float*)d_in[5];
    const float* filt_b1    = (const float*)d_in[6];
    const float* filt_W2    = (const float*)d_in[7];
    const float* filt_b2    = (const float*)d_in[8];
    const float* upd_W1     = (const float*)d_in[9];
    const float* upd_b1     = (const float*)d_in[10];
    const float* upd_W2     = (const float*)d_in[11];
    const float* upd_b2     = (const float*)d_in[12];
    const float* lam_W1     = (const float*)d_in[13];
    const float* lam_b1     = (const float*)d_in[14];
    const float* lam_W2     = (const float*)d_in[15];
    const float* lam_b2     = (const float*)d_in[16];
    const float* phi_W1     = (const float*)d_in[17];
    const float* phi_b1     = (const float*)d_in[18];
    const float* phi_W2     = (const float*)d_in[19];
    const float* phi_b2     = (const float*)d_in[20];
    float* out = (float*)d_out;

    const int* row = edge_index;
    const int* col = edge_index + NE;

    char* ws = (char*)d_ws;
    size_t off = 0;
    auto alloc = [&](size_t bytes) -> char* {
        char* p = ws + off;
        off = (off + bytes + 255) & ~(size_t)255;
        return p;
    };
    float*   dist_g  = (float*)alloc((size_t)NE * 4);
    float*   dirs    = (float*)alloc((size_t)NE * 3 * 4);
    int*     csr_eid = (int*)  alloc((size_t)NE * 4);
    int*     row_ptr = (int*)  alloc((size_t)(NA + 1) * 4);
    int*     deg     = (int*)  alloc((size_t)NA * 4);
    int*     cursor  = (int*)  alloc((size_t)NA * 4);
    float*   s       = (float*)alloc((size_t)NA * HD * 4);
    ushort4* vpack   = (ushort4*)alloc((size_t)NA * HD * 8);
    float*   m_s     = (float*)alloc((size_t)NA * HD * 4);
    float*   m_v     = (float*)alloc((size_t)NA * HD * 3 * 4);
    unsigned short* fW2frag = (unsigned short*)alloc((size_t)NL * 24 * 4 * 64 * 8 * 2);
    unsigned short* uW1frag = (unsigned short*)alloc((size_t)NL * 8 * 12 * 64 * 8 * 2);
    unsigned short* uW2frag = (unsigned short*)alloc((size_t)NL * 24 * 4 * 64 * 8 * 2);

    const int EB = (NE + 255) / 256;
    const int NB = (NA * HD) / 256;
    const int MSG_BLOCKS = NE / EPB;           // 12500 (exact)
    const int UPD_BLOCKS = (NA + 63) / 64;     // 782

    hipMemsetAsync(deg, 0, (size_t)NA * 4, stream);
    hipMemsetAsync(m_s, 0, (size_t)NA * HD * 4, stream);
    hipMemsetAsync(m_v, 0, (size_t)NA * HD * 3 * 4, stream);
    geom_kernel<<<EB, 256, 0, stream>>>(pos, row, col, dist_g, dirs);
    deg_kernel<<<EB, 256, 0, stream>>>(row, deg);
    scan_kernel<<<1, 1024, 0, stream>>>(deg, row_ptr, cursor);
    scatter_kernel<<<EB, 256, 0, stream>>>(row, cursor, csr_eid);
    embed_kernel<<<NB, 256, 0, stream>>>(z, emb, s, vpack);
    pack_bfrag_kernel<<<96, 256, 0, stream>>>(filt_W2, 128, 384, NL, fW2frag);
    pack_bfrag_kernel<<<96, 256, 0, stream>>>(upd_W1, 384, 128, NL, uW1frag);
    pack_bfrag_kernel<<<96, 256, 0, stream>>>(upd_W2, 128, 384, NL, uW2frag);

    for (int i = 0; i < NL; ++i) {
        const float* fW1 = filt_W1 + (size_t)i * 20 * HD;
        const float* fb1 = filt_b1 + (size_t)i * HD;
        const float* fb2 = filt_b2 + (size_t)i * 384;
        const unsigned short* fW2f = fW2frag + (size_t)i * 24 * 4 * 64 * 8;
        const unsigned short* uW1f = uW1frag + (size_t)i * 8 * 12 * 64 * 8;
        const unsigned short* uW2f = uW2frag + (size_t)i * 24 * 4 * 64 * 8;
        const float* ub1 = upd_b1 + (size_t)i * HD;
        const float* ub2 = upd_b2 + (size_t)i * 384;

        layer_msg_kernel<<<MSG_BLOCKS, 256, 0, stream>>>(
            dist_g, csr_eid, row_ptr, row, col, dirs,
            fW1, fb1, fW2f, fb2, vpack, m_s, m_v);
        upd12_kernel<<<UPD_BLOCKS, 256, 0, stream>>>(
            s, vpack, m_s, m_v, uW1f, ub1, uW2f, ub2);
    }

    readout_kernel<<<NM, 128, 0, stream>>>(s, batch,
        lam_W1, lam_b1, lam_W2, lam_b2,
        phi_W1, phi_b1, phi_W2, phi_b2, out);
}

// Round 7
// 1267.253 us; speedup vs baseline: 7.4032x; 1.1767x over previous
//
#include <hip/hip_runtime.h>
#include <hip/hip_bf16.h>

// ---------------- constants (match reference) ----------------
static constexpr int NA = 50000;   // atoms
static constexpr int NE = 400000;  // edges
static constexpr int HD = 128;     // hidden
static constexpr int NL = 4;       // layers
static constexpr int NM = 500;     // molecules
static constexpr int EPB = 32;     // edges per msg block (NE/EPB = 12500 exact)
static constexpr int HSW = 194;    // u32 stride per LDS h edge-row (192 data + 2 pad)

typedef __hip_bfloat16 bf16;
typedef short short8 __attribute__((ext_vector_type(8)));
typedef float float4v __attribute__((ext_vector_type(4)));

__device__ __forceinline__ unsigned short f2bf_bits(float x) {
    union { float f; unsigned int u; } c; c.f = x;
    unsigned int lsb = (c.u >> 16) & 1u;
    return (unsigned short)((c.u + 0x7fffu + lsb) >> 16);
}
__device__ __forceinline__ float bf2f(unsigned short b) {
    union { unsigned int u; float f; } c; c.u = ((unsigned int)b) << 16;
    return c.f;
}
__device__ __forceinline__ float lo16f(unsigned int u) {
    union { unsigned int x; float f; } c; c.x = u << 16; return c.f;
}
__device__ __forceinline__ float hi16f(unsigned int u) {
    union { unsigned int x; float f; } c; c.x = u & 0xffff0000u; return c.f;
}
__device__ __forceinline__ float silu_f(float x) {
    float sg = 1.0f / (1.0f + __expf(-x));
    return x * sg;
}

// ---------------- geometry: dist, dirs ----------------
__global__ void geom_kernel(const float* __restrict__ pos,
                            const int* __restrict__ row, const int* __restrict__ col,
                            float* __restrict__ dist_g, float* __restrict__ dirs) {
    int e = blockIdx.x * 256 + threadIdx.x;
    if (e >= NE) return;
    int r = row[e], c = col[e];
    float dx = pos[c*3+0] - pos[r*3+0];
    float dy = pos[c*3+1] - pos[r*3+1];
    float dz = pos[c*3+2] - pos[r*3+2];
    float dist = sqrtf(dx*dx + dy*dy + dz*dz);
    float inv = 1.0f / (dist + 1e-8f);
    dist_g[e] = dist;
    dirs[e*3+0] = dx*inv; dirs[e*3+1] = dy*inv; dirs[e*3+2] = dz*inv;
}

// ---------------- CSR build (multi-block scan) ----------------
__global__ void deg_kernel(const int* __restrict__ row, int* __restrict__ deg) {
    int e = blockIdx.x * 256 + threadIdx.x;
    if (e >= NE) return;
    atomicAdd(&deg[row[e]], 1);
}

__global__ __launch_bounds__(1024) void blockscan_kernel(const int* __restrict__ deg,
                                                         int* __restrict__ incl,
                                                         int* __restrict__ btot) {
    __shared__ int sh[1024];
    int t = threadIdx.x;
    int i = blockIdx.x * 1024 + t;
    int x = (i < NA) ? deg[i] : 0;
    sh[t] = x;
    __syncthreads();
    for (int off = 1; off < 1024; off <<= 1) {
        int v_ = (t >= off) ? sh[t - off] : 0;
        __syncthreads();
        sh[t] += v_;
        __syncthreads();
    }
    if (i < NA) incl[i] = sh[t];
    if (t == 1023) btot[blockIdx.x] = sh[t];
}

__global__ void totals_kernel(int* __restrict__ btot, int nb) {
    if (threadIdx.x == 0 && blockIdx.x == 0) {
        int acc = 0;
        for (int b = 0; b < nb; ++b) { int tv = btot[b]; btot[b] = acc; acc += tv; }
    }
}

__global__ void finalize_kernel(const int* __restrict__ deg, const int* __restrict__ incl,
                                const int* __restrict__ btot,
                                int* __restrict__ row_ptr, int* __restrict__ cursor) {
    int i = blockIdx.x * 256 + threadIdx.x;
    if (i >= NA) return;
    int inc = btot[i >> 10] + incl[i];
    row_ptr[i + 1] = inc;
    cursor[i] = inc - deg[i];
    if (i == 0) row_ptr[0] = 0;
}

__global__ void scatter_kernel(const int* __restrict__ row, int* __restrict__ cursor,
                               int* __restrict__ csr_eid) {
    int e = blockIdx.x * 256 + threadIdx.x;
    if (e >= NE) return;
    int p = atomicAdd(&cursor[row[e]], 1);
    csr_eid[p] = e;
}

// ---------------- node init: s = emb[z]; vp2 pair layout ----------------
// vp2[n*64+cp] (16B) = {s(cp)|v0(cp)<<16, v1(cp)|v2(cp)<<16, s(cp+64)|v0<<16, v1|v2<<16}
__global__ void embed_kernel(const int* __restrict__ z, const float* __restrict__ emb,
                             float* __restrict__ s, uint4* __restrict__ vp2) {
    int idx = blockIdx.x * 256 + threadIdx.x;
    if (idx >= NA * 64) return;
    int n = idx >> 6, cp = idx & 63;
    float vlo = emb[z[n] * HD + cp];
    float vhi = emb[z[n] * HD + 64 + cp];
    s[(size_t)n * HD + cp] = vlo;
    s[(size_t)n * HD + 64 + cp] = vhi;
    uint4 q;
    q.x = (unsigned int)f2bf_bits(vlo);
    q.y = 0u;
    q.z = (unsigned int)f2bf_bits(vhi);
    q.w = 0u;
    vp2[idx] = q;
}

// ---------------- generic weight -> B-fragment-linear bf16 ----------------
__global__ void pack_bfrag_kernel(const float* __restrict__ W, int K, int N,
                                  int layers, unsigned short* __restrict__ out) {
    int NT = N >> 4, KC = K >> 5;
    int total = layers * NT * KC * 64;
    int idx = blockIdx.x * 256 + threadIdx.x;
    if (idx >= total) return;
    int lane = idx & 63;
    int kc = (idx >> 6) % KC;
    int nt = ((idx >> 6) / KC) % NT;
    int layer = (idx >> 6) / (KC * NT);
    const float* Wl = W + (size_t)layer * K * N;
    int n = nt * 16 + (lane & 15);
    int k0 = kc * 32 + (lane >> 4) * 8;
    short8 pk;
#pragma unroll
    for (int j = 0; j < 8; ++j)
        pk[j] = (short)f2bf_bits(Wl[(size_t)(k0 + j) * N + n]);
    *(short8*)(&out[(size_t)idx * 8]) = pk;
}

// ---------------- filter W1 (20x128) -> B-frag, K padded to 32 with zeros -----------
__global__ void pack_w1frag_kernel(const float* __restrict__ W1all,
                                   unsigned short* __restrict__ out) {
    int idx = blockIdx.x * 256 + threadIdx.x;   // NL*8*64 = 2048
    if (idx >= NL * 8 * 64) return;
    int lane = idx & 63;
    int nt = (idx >> 6) & 7;
    int layer = idx >> 9;
    const float* W1 = W1all + (size_t)layer * 20 * HD;
    int n = nt * 16 + (lane & 15);
    int k0 = (lane >> 4) * 8;
    short8 pk;
#pragma unroll
    for (int j = 0; j < 8; ++j) {
        int k = k0 + j;
        pk[j] = (k < 20) ? (short)f2bf_bits(W1[(size_t)k * HD + n]) : (short)0;
    }
    *(short8*)(&out[(size_t)idx * 8]) = pk;
}

// ---------------- fused filter(MFMA x2) + aggregate: 32 CSR edges/block -------------
__global__ __launch_bounds__(256, 6) void layer_msg_kernel(
    const float* __restrict__ dist_g, const int* __restrict__ csr_eid,
    const int* __restrict__ row_ptr, const int* __restrict__ row,
    const int* __restrict__ col, const float* __restrict__ dirs,
    const unsigned short* __restrict__ W1frag, const float* __restrict__ b1,
    const unsigned short* __restrict__ W2frag, const float* __restrict__ b2,
    const uint4* __restrict__ vp2,
    float* __restrict__ m_s, float* __restrict__ m_v)
{
    // union: phases 1-2: t_frag (8 KB). phases 3-4: h (EPB x HSW u32, channel-paired)
    __shared__ __align__(16) unsigned int smem32[EPB * HSW];   // 24832 B
    unsigned short* t_frag = (unsigned short*)smem32;
    __shared__ float dist_s[EPB];
    __shared__ int   col_s[EPB];
    __shared__ int   rid_s[EPB];
    __shared__ float dirs_s[EPB * 3];

    int tid = threadIdx.x;
    int base = blockIdx.x * EPB;

    if (tid < EPB) {
        int eid = csr_eid[base + tid];
        dist_s[tid] = dist_g[eid];
        col_s[tid] = col[eid];
        rid_s[tid] = row[eid];
        dirs_s[tid*3+0] = dirs[eid*3+0];
        dirs_s[tid*3+1] = dirs[eid*3+1];
        dirs_s[tid*3+2] = dirs[eid*3+2];
    }
    __syncthreads();

    int lane = tid & 63, w = tid >> 6;
    int colb = lane & 15, quad = lane >> 4;
    int et = w & 1, oh = w >> 1;

    // ---- phase 1: GEMM1 via MFMA. wave: edges [16et,16et+16) x n1 in [64oh, 64oh+64) ----
    {
        float d = dist_s[et * 16 + colb];   // lane&15 = A-frag edge row
        short8 arbf;
#pragma unroll
        for (int j = 0; j < 8; ++j) {
            int k = quad * 8 + j;
            float t = d - (5.0f / 19.0f) * (float)k;
            arbf[j] = (short)f2bf_bits(__expf(-t * t));
        }
        float4v acc1[4];
#pragma unroll
        for (int nt2 = 0; nt2 < 4; ++nt2) {
            short8 b = *(const short8*)(W1frag + ((size_t)((oh * 4 + nt2) * 64 + lane)) * 8);
            float4v z = {0.f, 0.f, 0.f, 0.f};
            acc1[nt2] = __builtin_amdgcn_mfma_f32_16x16x32_bf16(arbf, b, z, 0, 0, 0);
        }
#pragma unroll
        for (int nt2 = 0; nt2 < 4; ++nt2) {
            int n1 = (oh * 4 + nt2) * 16 + colb;    // C col = lane&15
            float bias = b1[n1];
            int kc2 = n1 >> 5, kq = (n1 >> 3) & 3, j2 = n1 & 7;
#pragma unroll
            for (int r = 0; r < 4; ++r) {
                float val = silu_f(acc1[nt2][r] + bias);
                int em = quad * 4 + r;              // C row = edge within half
                t_frag[(((et * 4 + kc2) * 64) + kq * 16 + em) * 8 + j2] = f2bf_bits(val);
            }
        }
    }
    __syncthreads();

    // ---- phase 2: load own A-frags for GEMM2 ----
    short8 a[4];
#pragma unroll
    for (int kc = 0; kc < 4; ++kc)
        a[kc] = *(const short8*)(&t_frag[((et * 4 + kc) * 64 + lane) * 8]);
    __syncthreads();   // frag reads done -> smem becomes h

    // ---- phase 3: MFMA GEMM2, write h (bf16, channel-paired u32 rows) to LDS ----
    unsigned short* h16 = (unsigned short*)smem32;
    int ntb = (w >> 1) * 12;
    for (int i = 0; i < 12; ++i) {
        int nt = ntb + i;
        float4v acc = {0.f, 0.f, 0.f, 0.f};
#pragma unroll
        for (int kc = 0; kc < 4; ++kc) {
            short8 b = *(const short8*)(W2frag + ((size_t)(nt * 4 + kc) * 64 + lane) * 8);
            acc = __builtin_amdgcn_mfma_f32_16x16x32_bf16(a[kc], b, acc, 0, 0, 0);
        }
        int n = nt * 16 + colb;
        int seg = n >> 7, nch = n & 127;
        int cp = nch & 63, half = nch >> 6;
        float bias = b2[n];
        int e0 = et * 16 + quad * 4;
        unsigned short* hp = h16 + ((size_t)(e0 * HSW) + seg * 64 + cp) * 2 + half;
#pragma unroll
        for (int r = 0; r < 4; ++r)
            hp[r * HSW * 2] = f2bf_bits(acc[r] + bias);
    }
    __syncthreads();

    // ---- phase 4: aggregation, 4 wave-teams x 64 channel-pairs ----
    int cp = tid & 63, team = tid >> 6;
    const unsigned int* h32 = smem32;
    int node_lo = rid_s[0], node_hi = rid_s[EPB - 1];
    for (int n = node_lo + team; n <= node_hi; n += 4) {
        int p0 = row_ptr[n], p1 = row_ptr[n + 1];
        int lo = p0 - base; if (lo < 0) lo = 0;
        int hi = p1 - base; if (hi > EPB) hi = EPB;
        if (lo >= hi) continue;
        bool interior = (p0 >= base) && (p1 <= base + EPB);
        float as_l = 0.f, as_h = 0.f;
        float a0l = 0.f, a1l = 0.f, a2l = 0.f, a0h = 0.f, a1h = 0.f, a2h = 0.f;
        int e = lo;
        for (; e + 2 <= hi; e += 2) {
            uint4 qa = vp2[(size_t)col_s[e] * 64 + cp];
            uint4 qb = vp2[(size_t)col_s[e + 1] * 64 + cp];
#pragma unroll
            for (int j = 0; j < 2; ++j) {
                uint4 q = j ? qb : qa;
                int ee = e + j;
                unsigned int hx0 = h32[ee * HSW + cp];
                unsigned int hx1 = h32[ee * HSW + 64 + cp];
                unsigned int hx2 = h32[ee * HSW + 128 + cp];
                float d0 = dirs_s[ee*3], d1 = dirs_s[ee*3+1], d2 = dirs_s[ee*3+2];
                float sc_l = lo16f(q.x), v0_l = hi16f(q.x), v1_l = lo16f(q.y), v2_l = hi16f(q.y);
                float sc_h = lo16f(q.z), v0_h = hi16f(q.z), v1_h = lo16f(q.w), v2_h = hi16f(q.w);
                float svd_l = hi16f(hx2 << 16) * 0.f + lo16f(hx2) * sc_l; // lo psv * sc
                float svd_h = hi16f(hx2) * sc_h;
                as_l += lo16f(hx0) * sc_l;  as_h += hi16f(hx0) * sc_h;
                float pvv_l = lo16f(hx1), pvv_h = hi16f(hx1);
                a0l += pvv_l * v0_l + svd_l * d0;  a0h += pvv_h * v0_h + svd_h * d0;
                a1l += pvv_l * v1_l + svd_l * d1;  a1h += pvv_h * v1_h + svd_h * d1;
                a2l += pvv_l * v2_l + svd_l * d2;  a2h += pvv_h * v2_h + svd_h * d2;
            }
        }
        for (; e < hi; ++e) {
            uint4 q = vp2[(size_t)col_s[e] * 64 + cp];
            unsigned int hx0 = h32[e * HSW + cp];
            unsigned int hx1 = h32[e * HSW + 64 + cp];
            unsigned int hx2 = h32[e * HSW + 128 + cp];
            float d0 = dirs_s[e*3], d1 = dirs_s[e*3+1], d2 = dirs_s[e*3+2];
            float sc_l = lo16f(q.x), v0_l = hi16f(q.x), v1_l = lo16f(q.y), v2_l = hi16f(q.y);
            float sc_h = lo16f(q.z), v0_h = hi16f(q.z), v1_h = lo16f(q.w), v2_h = hi16f(q.w);
            float svd_l = lo16f(hx2) * sc_l;
            float svd_h = hi16f(hx2) * sc_h;
            as_l += lo16f(hx0) * sc_l;  as_h += hi16f(hx0) * sc_h;
            float pvv_l = lo16f(hx1), pvv_h = hi16f(hx1);
            a0l += pvv_l * v0_l + svd_l * d0;  a0h += pvv_h * v0_h + svd_h * d0;
            a1l += pvv_l * v1_l + svd_l * d1;  a1h += pvv_h * v1_h + svd_h * d1;
            a2l += pvv_l * v2_l + svd_l * d2;  a2h += pvv_h * v2_h + svd_h * d2;
        }
        size_t msx = (size_t)n * HD;
        size_t mvx = (size_t)n * 3 * HD;
        if (interior) {
            m_s[msx + cp] = as_l;          m_s[msx + 64 + cp] = as_h;
            m_v[mvx + cp] = a0l;           m_v[mvx + 64 + cp] = a0h;
            m_v[mvx + HD + cp] = a1l;      m_v[mvx + HD + 64 + cp] = a1h;
            m_v[mvx + 2*HD + cp] = a2l;    m_v[mvx + 2*HD + 64 + cp] = a2h;
        } else {
            atomicAdd(&m_s[msx + cp], as_l);          atomicAdd(&m_s[msx + 64 + cp], as_h);
            atomicAdd(&m_v[mvx + cp], a0l);           atomicAdd(&m_v[mvx + 64 + cp], a0h);
            atomicAdd(&m_v[mvx + HD + cp], a1l);      atomicAdd(&m_v[mvx + HD + 64 + cp], a1h);
            atomicAdd(&m_v[mvx + 2*HD + cp], a2l);    atomicAdd(&m_v[mvx + 2*HD + 64 + cp], a2h);
        }
    }
}

// ---------------- fused update MLP (MFMA x2) + s/v apply + m zeroing -------------
__global__ __launch_bounds__(256) void upd12_kernel(
    float* __restrict__ s, uint4* __restrict__ vp2,
    float* __restrict__ m_s, float* __restrict__ m_v,
    const unsigned short* __restrict__ W1frag, const float* __restrict__ b1,
    const unsigned short* __restrict__ W2frag, const float* __restrict__ b2)
{
    __shared__ __align__(16) unsigned short afrag[64 * 384];
    int tid = threadIdx.x;
    int r0 = blockIdx.x * 64;

#pragma unroll
    for (int t = 0; t < 12; ++t) {
        int id = tid + 256 * t;
        int r = id / 48;
        int kg = id % 48;
        int rr = r0 + r; if (rr >= NA) rr = NA - 1;
        float vals[8];
        if (kg < 16) {
            const float* p = s + (size_t)rr * HD + kg * 8;
#pragma unroll
            for (int j = 0; j < 8; ++j) vals[j] = p[j];
        } else if (kg < 32) {
            const float* p = m_s + (size_t)rr * HD + (kg - 16) * 8;
#pragma unroll
            for (int j = 0; j < 8; ++j) vals[j] = p[j];
        } else {
            int cb = (kg - 32) * 8;
            const float* p = m_v + (size_t)rr * 3 * HD + cb;
#pragma unroll
            for (int j = 0; j < 8; ++j) {
                float x = p[j], y = p[HD + j], z = p[2*HD + j];
                vals[j] = sqrtf(x*x + y*y + z*z);
            }
        }
        int kc = kg >> 2, hi = kg & 3, m = r & 15, rt = r >> 4;
        short8 pk;
#pragma unroll
        for (int j = 0; j < 8; ++j) pk[j] = (short)f2bf_bits(vals[j]);
        *(short8*)(&afrag[(((rt * 12 + kc) * 64) + hi * 16 + m) * 8]) = pk;
    }
    __syncthreads();

    int lane = tid & 63, w = tid >> 6;
    int colb = lane & 15, quad = lane >> 4;

    float4v acc1[8];
#pragma unroll
    for (int nt = 0; nt < 8; ++nt) acc1[nt] = (float4v){0.f,0.f,0.f,0.f};
    for (int kc = 0; kc < 12; ++kc) {
        short8 a = *(const short8*)(&afrag[((w * 12 + kc) * 64 + lane) * 8]);
#pragma unroll
        for (int nt = 0; nt < 8; ++nt) {
            short8 b = *(const short8*)(W1frag + ((size_t)(nt * 12 + kc) * 64 + lane) * 8);
            acc1[nt] = __builtin_amdgcn_mfma_f32_16x16x32_bf16(a, b, acc1[nt], 0, 0, 0);
        }
    }
    __syncthreads();

#pragma unroll
    for (int nt = 0; nt < 8; ++nt) {
        int n1 = nt * 16 + colb;
        int kc2 = n1 >> 5, hi2 = (n1 >> 3) & 3, j2 = n1 & 7;
#pragma unroll
        for (int r = 0; r < 4; ++r) {
            float t1v = silu_f(acc1[nt][r] + b1[n1]);
            int m2 = quad * 4 + r;
            afrag[(((w * 4 + kc2) * 64) + hi2 * 16 + m2) * 8 + j2] = f2bf_bits(t1v);
        }
    }
    __syncthreads();

    short8 a2[4];
#pragma unroll
    for (int kc = 0; kc < 4; ++kc)
        a2[kc] = *(const short8*)(&afrag[((w * 4 + kc) * 64 + lane) * 8]);

    for (int i = 0; i < 4; ++i) {
        float4v dl = {0.f,0.f,0.f,0.f}, dh = {0.f,0.f,0.f,0.f};
        float4v al = {0.f,0.f,0.f,0.f}, ah = {0.f,0.f,0.f,0.f};
        float4v bl = {0.f,0.f,0.f,0.f}, bh = {0.f,0.f,0.f,0.f};
#pragma unroll
        for (int kc = 0; kc < 4; ++kc) {
            short8 w_dl = *(const short8*)(W2frag + ((size_t)((i     ) * 4 + kc) * 64 + lane) * 8);
            short8 w_dh = *(const short8*)(W2frag + ((size_t)((i +  4) * 4 + kc) * 64 + lane) * 8);
            short8 w_al = *(const short8*)(W2frag + ((size_t)((i +  8) * 4 + kc) * 64 + lane) * 8);
            short8 w_ah = *(const short8*)(W2frag + ((size_t)((i + 12) * 4 + kc) * 64 + lane) * 8);
            short8 w_bl = *(const short8*)(W2frag + ((size_t)((i + 16) * 4 + kc) * 64 + lane) * 8);
            short8 w_bh = *(const short8*)(W2frag + ((size_t)((i + 20) * 4 + kc) * 64 + lane) * 8);
            dl = __builtin_amdgcn_mfma_f32_16x16x32_bf16(a2[kc], w_dl, dl, 0, 0, 0);
            dh = __builtin_amdgcn_mfma_f32_16x16x32_bf16(a2[kc], w_dh, dh, 0, 0, 0);
            al = __builtin_amdgcn_mfma_f32_16x16x32_bf16(a2[kc], w_al, al, 0, 0, 0);
            ah = __builtin_amdgcn_mfma_f32_16x16x32_bf16(a2[kc], w_ah, ah, 0, 0, 0);
            bl = __builtin_amdgcn_mfma_f32_16x16x32_bf16(a2[kc], w_bl, bl, 0, 0, 0);
            bh = __builtin_amdgcn_mfma_f32_16x16x32_bf16(a2[kc], w_bh, bh, 0, 0, 0);
        }
        int cp = i * 16 + colb;   // in [0,64)
        float bd_l = b2[cp],        bd_h = b2[64 + cp];
        float ba_l = b2[128 + cp],  ba_h = b2[192 + cp];
        float bb_l = b2[256 + cp],  bb_h = b2[320 + cp];
#pragma unroll
        for (int r = 0; r < 4; ++r) {
            int rr = r0 + 16 * w + quad * 4 + r;
            if (rr < NA) {
                size_t sx = (size_t)rr * HD;
                size_t vx = (size_t)rr * 3 * HD;
                float news_l = s[sx + cp]      + dl[r] + bd_l;
                float news_h = s[sx + 64 + cp] + dh[r] + bd_h;
                s[sx + cp] = news_l;
                s[sx + 64 + cp] = news_h;
                float alv_l = al[r] + ba_l, alv_h = ah[r] + ba_h;
                float bev_l = bl[r] + bb_l, bev_h = bh[r] + bb_h;
                uint4 q = vp2[(size_t)rr * 64 + cp];
                float nv0_l = alv_l * hi16f(q.x) + bev_l * m_v[vx + cp];
                float nv1_l = alv_l * lo16f(q.y) + bev_l * m_v[vx + HD + cp];
                float nv2_l = alv_l * hi16f(q.y) + bev_l * m_v[vx + 2*HD + cp];
                float nv0_h = alv_h * hi16f(q.z) + bev_h * m_v[vx + 64 + cp];
                float nv1_h = alv_h * lo16f(q.w) + bev_h * m_v[vx + HD + 64 + cp];
                float nv2_h = alv_h * hi16f(q.w) + bev_h * m_v[vx + 2*HD + 64 + cp];
                uint4 nq;
                nq.x = (unsigned int)f2bf_bits(news_l) | ((unsigned int)f2bf_bits(nv0_l) << 16);
                nq.y = (unsigned int)f2bf_bits(nv1_l)  | ((unsigned int)f2bf_bits(nv2_l) << 16);
                nq.z = (unsigned int)f2bf_bits(news_h) | ((unsigned int)f2bf_bits(nv0_h) << 16);
                nq.w = (unsigned int)f2bf_bits(nv1_h)  | ((unsigned int)f2bf_bits(nv2_h) << 16);
                vp2[(size_t)rr * 64 + cp] = nq;
                m_s[sx + cp] = 0.f;            m_s[sx + 64 + cp] = 0.f;
                m_v[vx + cp] = 0.f;            m_v[vx + 64 + cp] = 0.f;
                m_v[vx + HD + cp] = 0.f;       m_v[vx + HD + 64 + cp] = 0.f;
                m_v[vx + 2*HD + cp] = 0.f;     m_v[vx + 2*HD + 64 + cp] = 0.f;
            }
        }
    }
}

// ---------------- readout ----------------
__global__ __launch_bounds__(128) void readout_kernel(
    const float* __restrict__ s, const int* __restrict__ batch,
    const float* __restrict__ lamW1, const float* __restrict__ lamb1,
    const float* __restrict__ lamW2, const float* __restrict__ lamb2,
    const float* __restrict__ phiW1, const float* __restrict__ phib1,
    const float* __restrict__ phiW2, const float* __restrict__ phib2,
    float* __restrict__ out)
{
    __shared__ int seg[2];
    __shared__ float hms[HD];
    __shared__ float red[HD];
    int m = blockIdx.x, c = threadIdx.x;
    if (c < 2) {
        int target = m + c;
        int lo = 0, hi = NA;
        while (lo < hi) { int mid = (lo + hi) >> 1; if (batch[mid] < target) lo = mid + 1; else hi = mid; }
        seg[c] = lo;
    }
    __syncthreads();
    int st = seg[0], en = seg[1];
    float acc = 0.f;
    for (int n2 = st; n2 < en; ++n2) acc += s[(size_t)n2 * HD + c];
    float hm = acc / (float)(en - st);
    hms[c] = hm;
    __syncthreads();

    float t = lamb1[c];
    for (int k = 0; k < HD; ++k) t += hms[k] * lamW1[k * HD + c];
    t = silu_f(t);
    red[c] = t * lamW2[c];
    __syncthreads();
    for (int off = 64; off > 0; off >>= 1) { if (c < off) red[c] += red[c + off]; __syncthreads(); }
    if (c == 0) out[m] = red[0] + lamb2[0];
    __syncthreads();

    t = phib1[c];
    for (int k = 0; k < HD; ++k) t += hms[k] * phiW1[k * HD + c];
    t = silu_f(t);
    red[c] = t * phiW2[c];
    __syncthreads();
    for (int off = 64; off > 0; off >>= 1) { if (c < off) red[c] += red[c + off]; __syncthreads(); }
    if (c == 0) { float x = red[0] + phib2[0]; out[NM + m] = 1.0f / (1.0f + __expf(-x)); }
}

// ---------------- host ----------------
extern "C" void kernel_launch(void* const* d_in, const int* in_sizes, int n_in,
                              void* d_out, int out_size, void* d_ws, size_t ws_size,
                              hipStream_t stream) {
    (void)in_sizes; (void)n_in; (void)out_size; (void)ws_size;
    const int*   z          = (const int*)  d_in[0];
    const float* pos        = (const float*)d_in[1];
    const int*   edge_index = (const int*)  d_in[2];
    const int*   batch      = (const int*)  d_in[3];
    const float* emb        = (const float*)d_in[4];
    const float* filt_W1    = (const float*)d_in[5];
    const float* filt_b1    = (const float*)d_in[6];
    const float* filt_W2    = (const float*)d_in[7];
    const float* filt_b2    = (const float*)d_in[8];
    const float* upd_W1     = (const float*)d_in[9];
    const float* upd_b1     = (const float*)d_in[10];
    const float* upd_W2     = (const float*)d_in[11];
    const float* upd_b2     = (const float*)d_in[12];
    const float* lam_W1     = (const float*)d_in[13];
    const float* lam_b1     = (const float*)d_in[14];
    const float* lam_W2     = (const float*)d_in[15];
    const float* lam_b2     = (const float*)d_in[16];
    const float* phi_W1     = (const float*)d_in[17];
    const float* phi_b1     = (const float*)d_in[18];
    const float* phi_W2     = (const float*)d_in[19];
    const float* phi_b2     = (const float*)d_in[20];
    float* out = (float*)d_out;

    const int* row = edge_index;
    const int* col = edge_index + NE;

    char* ws = (char*)d_ws;
    size_t off = 0;
    auto alloc = [&](size_t bytes) -> char* {
        char* p = ws + off;
        off = (off + bytes + 255) & ~(size_t)255;
        return p;
    };
    float* dist_g  = (float*)alloc((size_t)NE * 4);
    float* dirs    = (float*)alloc((size_t)NE * 3 * 4);
    int*   csr_eid = (int*)  alloc((size_t)NE * 4);
    int*   row_ptr = (int*)  alloc((size_t)(NA + 1) * 4);
    int*   deg     = (int*)  alloc((size_t)NA * 4);
    int*   cursor  = (int*)  alloc((size_t)NA * 4);
    int*   incl    = (int*)  alloc((size_t)NA * 4);
    int*   btot    = (int*)  alloc(256);
    float* s       = (float*)alloc((size_t)NA * HD * 4);
    uint4* vp2     = (uint4*)alloc((size_t)NA * 64 * 16);
    float* m_s     = (float*)alloc((size_t)NA * HD * 4);
    float* m_v     = (float*)alloc((size_t)NA * HD * 3 * 4);
    unsigned short* fW1frag = (unsigned short*)alloc((size_t)NL * 8 * 64 * 8 * 2);
    unsigned short* fW2frag = (unsigned short*)alloc((size_t)NL * 24 * 4 * 64 * 8 * 2);
    unsigned short* uW1frag = (unsigned short*)alloc((size_t)NL * 8 * 12 * 64 * 8 * 2);
    unsigned short* uW2frag = (unsigned short*)alloc((size_t)NL * 24 * 4 * 64 * 8 * 2);

    const int EB = (NE + 255) / 256;
    const int SCAN_BLOCKS = (NA + 1023) / 1024;  // 49
    const int MSG_BLOCKS = NE / EPB;             // 12500 (exact)
    const int UPD_BLOCKS = (NA + 63) / 64;       // 782

    hipMemsetAsync(deg, 0, (size_t)NA * 4, stream);
    hipMemsetAsync(m_s, 0, (size_t)NA * HD * 4, stream);
    hipMemsetAsync(m_v, 0, (size_t)NA * HD * 3 * 4, stream);
    geom_kernel<<<EB, 256, 0, stream>>>(pos, row, col, dist_g, dirs);
    deg_kernel<<<EB, 256, 0, stream>>>(row, deg);
    blockscan_kernel<<<SCAN_BLOCKS, 1024, 0, stream>>>(deg, incl, btot);
    totals_kernel<<<1, 64, 0, stream>>>(btot, SCAN_BLOCKS);
    finalize_kernel<<<(NA + 255) / 256, 256, 0, stream>>>(deg, incl, btot, row_ptr, cursor);
    scatter_kernel<<<EB, 256, 0, stream>>>(row, cursor, csr_eid);
    embed_kernel<<<(NA * 64 + 255) / 256, 256, 0, stream>>>(z, emb, s, vp2);
    pack_w1frag_kernel<<<8, 256, 0, stream>>>(filt_W1, fW1frag);
    pack_bfrag_kernel<<<96, 256, 0, stream>>>(filt_W2, 128, 384, NL, fW2frag);
    pack_bfrag_kernel<<<96, 256, 0, stream>>>(upd_W1, 384, 128, NL, uW1frag);
    pack_bfrag_kernel<<<96, 256, 0, stream>>>(upd_W2, 128, 384, NL, uW2frag);

    for (int i = 0; i < NL; ++i) {
        const float* fb1 = filt_b1 + (size_t)i * HD;
        const float* fb2 = filt_b2 + (size_t)i * 384;
        const unsigned short* fW1f = fW1frag + (size_t)i * 8 * 64 * 8;
        const unsigned short* fW2f = fW2frag + (size_t)i * 24 * 4 * 64 * 8;
        const unsigned short* uW1f = uW1frag + (size_t)i * 8 * 12 * 64 * 8;
        const unsigned short* uW2f = uW2frag + (size_t)i * 24 * 4 * 64 * 8;
        const float* ub1 = upd_b1 + (size_t)i * HD;
        const float* ub2 = upd_b2 + (size_t)i * 384;

        layer_msg_kernel<<<MSG_BLOCKS, 256, 0, stream>>>(
            dist_g, csr_eid, row_ptr, row, col, dirs,
            fW1f, fb1, fW2f, fb2, vp2, m_s, m_v);
        upd12_kernel<<<UPD_BLOCKS, 256, 0, stream>>>(
            s, vp2, m_s, m_v, uW1f, ub1, uW2f, ub2);
    }

    readout_kernel<<<NM, 128, 0, stream>>>(s, batch,
        lam_W1, lam_b1, lam_W2, lam_b2,
        phi_W1, phi_b1, phi_W2, phi_b2, out);
}

// Round 8
// 1236.175 us; speedup vs baseline: 7.5893x; 1.0251x over previous
//
#include <hip/hip_runtime.h>
#include <hip/hip_bf16.h>

// ---------------- constants (match reference) ----------------
static constexpr int NA = 50000;   // atoms
static constexpr int NE = 400000;  // edges
static constexpr int HD = 128;     // hidden
static constexpr int NL = 4;       // layers
static constexpr int NM = 500;     // molecules
static constexpr int EPB = 32;     // edges per msg block (NE/EPB = 12500 exact)
static constexpr int HSW = 194;    // u32 stride per LDS h edge-row (192 data + 2 pad)
static constexpr int BCAP = 16384; // capacity of boundary-node list

typedef __hip_bfloat16 bf16;
typedef short short8 __attribute__((ext_vector_type(8)));
typedef float float4v __attribute__((ext_vector_type(4)));
typedef float float2v __attribute__((ext_vector_type(2)));

__device__ __forceinline__ unsigned short f2bf_bits(float x) {
    union { float f; unsigned int u; } c; c.f = x;
    unsigned int lsb = (c.u >> 16) & 1u;
    return (unsigned short)((c.u + 0x7fffu + lsb) >> 16);
}
__device__ __forceinline__ float lo16f(unsigned int u) {
    union { unsigned int x; float f; } c; c.x = u << 16; return c.f;
}
__device__ __forceinline__ float hi16f(unsigned int u) {
    union { unsigned int x; float f; } c; c.x = u & 0xffff0000u; return c.f;
}
__device__ __forceinline__ float silu_f(float x) {
    float sg = 1.0f / (1.0f + __expf(-x));
    return x * sg;
}

// ---------------- geometry: dist, dirs ----------------
__global__ void geom_kernel(const float* __restrict__ pos,
                            const int* __restrict__ row, const int* __restrict__ col,
                            float* __restrict__ dist_g, float* __restrict__ dirs) {
    int e = blockIdx.x * 256 + threadIdx.x;
    if (e >= NE) return;
    int r = row[e], c = col[e];
    float dx = pos[c*3+0] - pos[r*3+0];
    float dy = pos[c*3+1] - pos[r*3+1];
    float dz = pos[c*3+2] - pos[r*3+2];
    float dist = sqrtf(dx*dx + dy*dy + dz*dz);
    float inv = 1.0f / (dist + 1e-8f);
    dist_g[e] = dist;
    dirs[e*3+0] = dx*inv; dirs[e*3+1] = dy*inv; dirs[e*3+2] = dz*inv;
}

// ---------------- CSR build (multi-block scan) ----------------
__global__ void deg_kernel(const int* __restrict__ row, int* __restrict__ deg) {
    int e = blockIdx.x * 256 + threadIdx.x;
    if (e >= NE) return;
    atomicAdd(&deg[row[e]], 1);
}

__global__ __launch_bounds__(1024) void blockscan_kernel(const int* __restrict__ deg,
                                                         int* __restrict__ incl,
                                                         int* __restrict__ btot) {
    __shared__ int sh[1024];
    int t = threadIdx.x;
    int i = blockIdx.x * 1024 + t;
    int x = (i < NA) ? deg[i] : 0;
    sh[t] = x;
    __syncthreads();
    for (int off = 1; off < 1024; off <<= 1) {
        int v_ = (t >= off) ? sh[t - off] : 0;
        __syncthreads();
        sh[t] += v_;
        __syncthreads();
    }
    if (i < NA) incl[i] = sh[t];
    if (t == 1023) btot[blockIdx.x] = sh[t];
}

__global__ void totals_kernel(int* __restrict__ btot, int nb) {
    if (threadIdx.x == 0 && blockIdx.x == 0) {
        int acc = 0;
        for (int b = 0; b < nb; ++b) { int tv = btot[b]; btot[b] = acc; acc += tv; }
    }
}

__global__ void finalize_kernel(const int* __restrict__ deg, const int* __restrict__ incl,
                                const int* __restrict__ btot,
                                int* __restrict__ row_ptr, int* __restrict__ cursor) {
    int i = blockIdx.x * 256 + threadIdx.x;
    if (i >= NA) return;
    int inc = btot[i >> 10] + incl[i];
    row_ptr[i + 1] = inc;
    cursor[i] = inc - deg[i];
    if (i == 0) row_ptr[0] = 0;
}

__global__ void scatter_kernel(const int* __restrict__ row, int* __restrict__ cursor,
                               int* __restrict__ csr_eid) {
    int e = blockIdx.x * 256 + threadIdx.x;
    if (e >= NE) return;
    int p = atomicAdd(&cursor[row[e]], 1);
    csr_eid[p] = e;
}

// ---------------- boundary-node list: nodes whose CSR range spans a block edge ------
__global__ void mark_boundary_kernel(const int* __restrict__ row_ptr,
                                     int* __restrict__ blist, int* __restrict__ bcount) {
    int n = blockIdx.x * 256 + threadIdx.x;
    if (n >= NA) return;
    int p0 = row_ptr[n], p1 = row_ptr[n + 1];
    if (p0 / EPB != (p1 - 1) / EPB) {
        int i = atomicAdd(bcount, 1);
        if (i < BCAP) blist[i] = n;
    }
}

// zero m_s/m_v rows of boundary nodes only (interior nodes are '=' written)
__global__ void zero_boundary_kernel(const int* __restrict__ blist,
                                     const int* __restrict__ bcount,
                                     float* __restrict__ m_s, float* __restrict__ m_v) {
    int idx = blockIdx.x * 256 + threadIdx.x;
    int cnt = *bcount; if (cnt > BCAP) cnt = BCAP;
    int ni = idx >> 7, c = idx & 127;
    if (ni >= cnt) return;
    int n = blist[ni];
    m_s[(size_t)n * HD + c] = 0.f;
    size_t vx = (size_t)n * 3 * HD + c;
    m_v[vx] = 0.f; m_v[vx + HD] = 0.f; m_v[vx + 2*HD] = 0.f;
}

// ---------------- node init: s = emb[z]; vp2 pair layout ----------------
__global__ void embed_kernel(const int* __restrict__ z, const float* __restrict__ emb,
                             float* __restrict__ s, uint4* __restrict__ vp2) {
    int idx = blockIdx.x * 256 + threadIdx.x;
    if (idx >= NA * 64) return;
    int n = idx >> 6, cp = idx & 63;
    float vlo = emb[z[n] * HD + cp];
    float vhi = emb[z[n] * HD + 64 + cp];
    s[(size_t)n * HD + cp] = vlo;
    s[(size_t)n * HD + 64 + cp] = vhi;
    uint4 q;
    q.x = (unsigned int)f2bf_bits(vlo);
    q.y = 0u;
    q.z = (unsigned int)f2bf_bits(vhi);
    q.w = 0u;
    vp2[idx] = q;
}

// ---------------- generic weight -> B-fragment-linear bf16 ----------------
__global__ void pack_bfrag_kernel(const float* __restrict__ W, int K, int N,
                                  int layers, unsigned short* __restrict__ out) {
    int NT = N >> 4, KC = K >> 5;
    int total = layers * NT * KC * 64;
    int idx = blockIdx.x * 256 + threadIdx.x;
    if (idx >= total) return;
    int lane = idx & 63;
    int kc = (idx >> 6) % KC;
    int nt = ((idx >> 6) / KC) % NT;
    int layer = (idx >> 6) / (KC * NT);
    const float* Wl = W + (size_t)layer * K * N;
    int n = nt * 16 + (lane & 15);
    int k0 = kc * 32 + (lane >> 4) * 8;
    short8 pk;
#pragma unroll
    for (int j = 0; j < 8; ++j)
        pk[j] = (short)f2bf_bits(Wl[(size_t)(k0 + j) * N + n]);
    *(short8*)(&out[(size_t)idx * 8]) = pk;
}

// ---------------- filter W1 (20x128) -> B-frag, K padded to 32 with zeros -----------
__global__ void pack_w1frag_kernel(const float* __restrict__ W1all,
                                   unsigned short* __restrict__ out) {
    int idx = blockIdx.x * 256 + threadIdx.x;   // NL*8*64 = 2048
    if (idx >= NL * 8 * 64) return;
    int lane = idx & 63;
    int nt = (idx >> 6) & 7;
    int layer = idx >> 9;
    const float* W1 = W1all + (size_t)layer * 20 * HD;
    int n = nt * 16 + (lane & 15);
    int k0 = (lane >> 4) * 8;
    short8 pk;
#pragma unroll
    for (int j = 0; j < 8; ++j) {
        int k = k0 + j;
        pk[j] = (k < 20) ? (short)f2bf_bits(W1[(size_t)k * HD + n]) : (short)0;
    }
    *(short8*)(&out[(size_t)idx * 8]) = pk;
}

// ---------------- fused filter(MFMA x2) + aggregate: 32 CSR edges/block -------------
__global__ __launch_bounds__(256, 6) void layer_msg_kernel(
    const float* __restrict__ dist_g, const int* __restrict__ csr_eid,
    const int* __restrict__ row_ptr, const int* __restrict__ row,
    const int* __restrict__ col, const float* __restrict__ dirs,
    const unsigned short* __restrict__ W1frag, const float* __restrict__ b1,
    const unsigned short* __restrict__ W2frag, const float* __restrict__ b2,
    const uint4* __restrict__ vp2,
    float* __restrict__ m_s, float* __restrict__ m_v)
{
    __shared__ __align__(16) unsigned int smem32[EPB * HSW];   // 24832 B
    unsigned short* t_frag = (unsigned short*)smem32;
    __shared__ float dist_s[EPB];
    __shared__ int   col_s[EPB];
    __shared__ int   rid_s[EPB];
    __shared__ float dirs_s[EPB * 3];

    int tid = threadIdx.x;
    int base = blockIdx.x * EPB;

    if (tid < EPB) {
        int eid = csr_eid[base + tid];
        dist_s[tid] = dist_g[eid];
        col_s[tid] = col[eid];
        rid_s[tid] = row[eid];
        dirs_s[tid*3+0] = dirs[eid*3+0];
        dirs_s[tid*3+1] = dirs[eid*3+1];
        dirs_s[tid*3+2] = dirs[eid*3+2];
    }
    __syncthreads();

    int lane = tid & 63, w = tid >> 6;
    int colb = lane & 15, quad = lane >> 4;
    int et = w & 1, oh = w >> 1;

    // ---- phase 1: GEMM1 via MFMA ----
    {
        float d = dist_s[et * 16 + colb];
        short8 arbf;
#pragma unroll
        for (int j = 0; j < 8; ++j) {
            int k = quad * 8 + j;
            float t = d - (5.0f / 19.0f) * (float)k;
            arbf[j] = (short)f2bf_bits(__expf(-t * t));
        }
        float4v acc1[4];
#pragma unroll
        for (int nt2 = 0; nt2 < 4; ++nt2) {
            short8 b = *(const short8*)(W1frag + ((size_t)((oh * 4 + nt2) * 64 + lane)) * 8);
            float4v z = {0.f, 0.f, 0.f, 0.f};
            acc1[nt2] = __builtin_amdgcn_mfma_f32_16x16x32_bf16(arbf, b, z, 0, 0, 0);
        }
#pragma unroll
        for (int nt2 = 0; nt2 < 4; ++nt2) {
            int n1 = (oh * 4 + nt2) * 16 + colb;
            float bias = b1[n1];
            int kc2 = n1 >> 5, kq = (n1 >> 3) & 3, j2 = n1 & 7;
#pragma unroll
            for (int r = 0; r < 4; ++r) {
                float val = silu_f(acc1[nt2][r] + bias);
                int em = quad * 4 + r;
                t_frag[(((et * 4 + kc2) * 64) + kq * 16 + em) * 8 + j2] = f2bf_bits(val);
            }
        }
    }
    __syncthreads();

    // ---- phase 2: load own A-frags for GEMM2 ----
    short8 a[4];
#pragma unroll
    for (int kc = 0; kc < 4; ++kc)
        a[kc] = *(const short8*)(&t_frag[((et * 4 + kc) * 64 + lane) * 8]);
    __syncthreads();

    // ---- phase 3: MFMA GEMM2, write h (bf16, channel-paired u32 rows) to LDS ----
    unsigned short* h16 = (unsigned short*)smem32;
    int ntb = (w >> 1) * 12;
    for (int i = 0; i < 12; ++i) {
        int nt = ntb + i;
        float4v acc = {0.f, 0.f, 0.f, 0.f};
#pragma unroll
        for (int kc = 0; kc < 4; ++kc) {
            short8 b = *(const short8*)(W2frag + ((size_t)(nt * 4 + kc) * 64 + lane) * 8);
            acc = __builtin_amdgcn_mfma_f32_16x16x32_bf16(a[kc], b, acc, 0, 0, 0);
        }
        int n = nt * 16 + colb;
        int seg = n >> 7, nch = n & 127;
        int cp = nch & 63, half = nch >> 6;
        float bias = b2[n];
        int e0 = et * 16 + quad * 4;
        unsigned short* hp = h16 + ((size_t)(e0 * HSW) + seg * 64 + cp) * 2 + half;
#pragma unroll
        for (int r = 0; r < 4; ++r)
            hp[r * HSW * 2] = f2bf_bits(acc[r] + bias);
    }
    __syncthreads();

    // ---- phase 4: aggregation, 4 wave-teams x 64 channel-pairs, float2 packed ----
    int cp = tid & 63, team = tid >> 6;
    const unsigned int* h32 = smem32;
    int node_lo = rid_s[0], node_hi = rid_s[EPB - 1];
    for (int n = node_lo + team; n <= node_hi; n += 4) {
        int p0 = row_ptr[n], p1 = row_ptr[n + 1];
        int lo = p0 - base; if (lo < 0) lo = 0;
        int hi = p1 - base; if (hi > EPB) hi = EPB;
        if (lo >= hi) continue;
        bool interior = (p0 >= base) && (p1 <= base + EPB);
        float2v as2 = {0.f, 0.f}, a02 = {0.f, 0.f}, a12 = {0.f, 0.f}, a22 = {0.f, 0.f};
        int e = lo;
        for (; e + 2 <= hi; e += 2) {
            uint4 qa = vp2[(size_t)col_s[e] * 64 + cp];
            uint4 qb = vp2[(size_t)col_s[e + 1] * 64 + cp];
#pragma unroll
            for (int j = 0; j < 2; ++j) {
                uint4 q = j ? qb : qa;
                int ee = e + j;
                unsigned int hx0 = h32[ee * HSW + cp];
                unsigned int hx1 = h32[ee * HSW + 64 + cp];
                unsigned int hx2 = h32[ee * HSW + 128 + cp];
                float2v sc2;  sc2.x = lo16f(q.x);   sc2.y = lo16f(q.z);
                float2v v02;  v02.x = hi16f(q.x);   v02.y = hi16f(q.z);
                float2v v12;  v12.x = lo16f(q.y);   v12.y = lo16f(q.w);
                float2v v22;  v22.x = hi16f(q.y);   v22.y = hi16f(q.w);
                float2v pss2; pss2.x = lo16f(hx0);  pss2.y = hi16f(hx0);
                float2v pvv2; pvv2.x = lo16f(hx1);  pvv2.y = hi16f(hx1);
                float2v psv2; psv2.x = lo16f(hx2);  psv2.y = hi16f(hx2);
                float2v svd2 = psv2 * sc2;
                as2 += pss2 * sc2;
                float d0 = dirs_s[ee*3], d1 = dirs_s[ee*3+1], d2 = dirs_s[ee*3+2];
                a02 += pvv2 * v02 + svd2 * d0;
                a12 += pvv2 * v12 + svd2 * d1;
                a22 += pvv2 * v22 + svd2 * d2;
            }
        }
        for (; e < hi; ++e) {
            uint4 q = vp2[(size_t)col_s[e] * 64 + cp];
            unsigned int hx0 = h32[e * HSW + cp];
            unsigned int hx1 = h32[e * HSW + 64 + cp];
            unsigned int hx2 = h32[e * HSW + 128 + cp];
            float2v sc2;  sc2.x = lo16f(q.x);   sc2.y = lo16f(q.z);
            float2v v02;  v02.x = hi16f(q.x);   v02.y = hi16f(q.z);
            float2v v12;  v12.x = lo16f(q.y);   v12.y = lo16f(q.w);
            float2v v22;  v22.x = hi16f(q.y);   v22.y = hi16f(q.w);
            float2v pss2; pss2.x = lo16f(hx0);  pss2.y = hi16f(hx0);
            float2v pvv2; pvv2.x = lo16f(hx1);  pvv2.y = hi16f(hx1);
            float2v psv2; psv2.x = lo16f(hx2);  psv2.y = hi16f(hx2);
            float2v svd2 = psv2 * sc2;
            as2 += pss2 * sc2;
            float d0 = dirs_s[e*3], d1 = dirs_s[e*3+1], d2 = dirs_s[e*3+2];
            a02 += pvv2 * v02 + svd2 * d0;
            a12 += pvv2 * v12 + svd2 * d1;
            a22 += pvv2 * v22 + svd2 * d2;
        }
        size_t msx = (size_t)n * HD;
        size_t mvx = (size_t)n * 3 * HD;
        if (interior) {
            m_s[msx + cp] = as2.x;          m_s[msx + 64 + cp] = as2.y;
            m_v[mvx + cp] = a02.x;          m_v[mvx + 64 + cp] = a02.y;
            m_v[mvx + HD + cp] = a12.x;     m_v[mvx + HD + 64 + cp] = a12.y;
            m_v[mvx + 2*HD + cp] = a22.x;   m_v[mvx + 2*HD + 64 + cp] = a22.y;
        } else {
            atomicAdd(&m_s[msx + cp], as2.x);          atomicAdd(&m_s[msx + 64 + cp], as2.y);
            atomicAdd(&m_v[mvx + cp], a02.x);          atomicAdd(&m_v[mvx + 64 + cp], a02.y);
            atomicAdd(&m_v[mvx + HD + cp], a12.x);     atomicAdd(&m_v[mvx + HD + 64 + cp], a12.y);
            atomicAdd(&m_v[mvx + 2*HD + cp], a22.x);   atomicAdd(&m_v[mvx + 2*HD + 64 + cp], a22.y);
        }
    }
}

// ---------------- fused update MLP (MFMA x2) + s/v apply -------------
__global__ __launch_bounds__(256) void upd12_kernel(
    float* __restrict__ s, uint4* __restrict__ vp2,
    const float* __restrict__ m_s, const float* __restrict__ m_v,
    const unsigned short* __restrict__ W1frag, const float* __restrict__ b1,
    const unsigned short* __restrict__ W2frag, const float* __restrict__ b2)
{
    __shared__ __align__(16) unsigned short afrag[64 * 384];
    int tid = threadIdx.x;
    int r0 = blockIdx.x * 64;

#pragma unroll
    for (int t = 0; t < 12; ++t) {
        int id = tid + 256 * t;
        int r = id / 48;
        int kg = id % 48;
        int rr = r0 + r; if (rr >= NA) rr = NA - 1;
        float vals[8];
        if (kg < 16) {
            const float* p = s + (size_t)rr * HD + kg * 8;
#pragma unroll
            for (int j = 0; j < 8; ++j) vals[j] = p[j];
        } else if (kg < 32) {
            const float* p = m_s + (size_t)rr * HD + (kg - 16) * 8;
#pragma unroll
            for (int j = 0; j < 8; ++j) vals[j] = p[j];
        } else {
            int cb = (kg - 32) * 8;
            const float* p = m_v + (size_t)rr * 3 * HD + cb;
#pragma unroll
            for (int j = 0; j < 8; ++j) {
                float x = p[j], y = p[HD + j], z = p[2*HD + j];
                vals[j] = sqrtf(x*x + y*y + z*z);
            }
        }
        int kc = kg >> 2, hi = kg & 3, m = r & 15, rt = r >> 4;
        short8 pk;
#pragma unroll
        for (int j = 0; j < 8; ++j) pk[j] = (short)f2bf_bits(vals[j]);
        *(short8*)(&afrag[(((rt * 12 + kc) * 64) + hi * 16 + m) * 8]) = pk;
    }
    __syncthreads();

    int lane = tid & 63, w = tid >> 6;
    int colb = lane & 15, quad = lane >> 4;

    float4v acc1[8];
#pragma unroll
    for (int nt = 0; nt < 8; ++nt) acc1[nt] = (float4v){0.f,0.f,0.f,0.f};
    for (int kc = 0; kc < 12; ++kc) {
        short8 a = *(const short8*)(&afrag[((w * 12 + kc) * 64 + lane) * 8]);
#pragma unroll
        for (int nt = 0; nt < 8; ++nt) {
            short8 b = *(const short8*)(W1frag + ((size_t)(nt * 12 + kc) * 64 + lane) * 8);
            acc1[nt] = __builtin_amdgcn_mfma_f32_16x16x32_bf16(a, b, acc1[nt], 0, 0, 0);
        }
    }
    __syncthreads();

#pragma unroll
    for (int nt = 0; nt < 8; ++nt) {
        int n1 = nt * 16 + colb;
        int kc2 = n1 >> 5, hi2 = (n1 >> 3) & 3, j2 = n1 & 7;
#pragma unroll
        for (int r = 0; r < 4; ++r) {
            float t1v = silu_f(acc1[nt][r] + b1[n1]);
            int m2 = quad * 4 + r;
            afrag[(((w * 4 + kc2) * 64) + hi2 * 16 + m2) * 8 + j2] = f2bf_bits(t1v);
        }
    }
    __syncthreads();

    short8 a2[4];
#pragma unroll
    for (int kc = 0; kc < 4; ++kc)
        a2[kc] = *(const short8*)(&afrag[((w * 4 + kc) * 64 + lane) * 8]);

    for (int i = 0; i < 4; ++i) {
        float4v dl = {0.f,0.f,0.f,0.f}, dh = {0.f,0.f,0.f,0.f};
        float4v al = {0.f,0.f,0.f,0.f}, ah = {0.f,0.f,0.f,0.f};
        float4v bl = {0.f,0.f,0.f,0.f}, bh = {0.f,0.f,0.f,0.f};
#pragma unroll
        for (int kc = 0; kc < 4; ++kc) {
            short8 w_dl = *(const short8*)(W2frag + ((size_t)((i     ) * 4 + kc) * 64 + lane) * 8);
            short8 w_dh = *(const short8*)(W2frag + ((size_t)((i +  4) * 4 + kc) * 64 + lane) * 8);
            short8 w_al = *(const short8*)(W2frag + ((size_t)((i +  8) * 4 + kc) * 64 + lane) * 8);
            short8 w_ah = *(const short8*)(W2frag + ((size_t)((i + 12) * 4 + kc) * 64 + lane) * 8);
            short8 w_bl = *(const short8*)(W2frag + ((size_t)((i + 16) * 4 + kc) * 64 + lane) * 8);
            short8 w_bh = *(const short8*)(W2frag + ((size_t)((i + 20) * 4 + kc) * 64 + lane) * 8);
            dl = __builtin_amdgcn_mfma_f32_16x16x32_bf16(a2[kc], w_dl, dl, 0, 0, 0);
            dh = __builtin_amdgcn_mfma_f32_16x16x32_bf16(a2[kc], w_dh, dh, 0, 0, 0);
            al = __builtin_amdgcn_mfma_f32_16x16x32_bf16(a2[kc], w_al, al, 0, 0, 0);
            ah = __builtin_amdgcn_mfma_f32_16x16x32_bf16(a2[kc], w_ah, ah, 0, 0, 0);
            bl = __builtin_amdgcn_mfma_f32_16x16x32_bf16(a2[kc], w_bl, bl, 0, 0, 0);
            bh = __builtin_amdgcn_mfma_f32_16x16x32_bf16(a2[kc], w_bh, bh, 0, 0, 0);
        }
        int cp = i * 16 + colb;
        float bd_l = b2[cp],        bd_h = b2[64 + cp];
        float ba_l = b2[128 + cp],  ba_h = b2[192 + cp];
        float bb_l = b2[256 + cp],  bb_h = b2[320 + cp];
#pragma unroll
        for (int r = 0; r < 4; ++r) {
            int rr = r0 + 16 * w + quad * 4 + r;
            if (rr < NA) {
                size_t sx = (size_t)rr * HD;
                size_t vx = (size_t)rr * 3 * HD;
                float news_l = s[sx + cp]      + dl[r] + bd_l;
                float news_h = s[sx + 64 + cp] + dh[r] + bd_h;
                s[sx + cp] = news_l;
                s[sx + 64 + cp] = news_h;
                float alv_l = al[r] + ba_l, alv_h = ah[r] + ba_h;
                float bev_l = bl[r] + bb_l, bev_h = bh[r] + bb_h;
                uint4 q = vp2[(size_t)rr * 64 + cp];
                float nv0_l = alv_l * hi16f(q.x) + bev_l * m_v[vx + cp];
                float nv1_l = alv_l * lo16f(q.y) + bev_l * m_v[vx + HD + cp];
                float nv2_l = alv_l * hi16f(q.y) + bev_l * m_v[vx + 2*HD + cp];
                float nv0_h = alv_h * hi16f(q.z) + bev_h * m_v[vx + 64 + cp];
                float nv1_h = alv_h * lo16f(q.w) + bev_h * m_v[vx + HD + 64 + cp];
                float nv2_h = alv_h * hi16f(q.w) + bev_h * m_v[vx + 2*HD + 64 + cp];
                uint4 nq;
                nq.x = (unsigned int)f2bf_bits(news_l) | ((unsigned int)f2bf_bits(nv0_l) << 16);
                nq.y = (unsigned int)f2bf_bits(nv1_l)  | ((unsigned int)f2bf_bits(nv2_l) << 16);
                nq.z = (unsigned int)f2bf_bits(news_h) | ((unsigned int)f2bf_bits(nv0_h) << 16);
                nq.w = (unsigned int)f2bf_bits(nv1_h)  | ((unsigned int)f2bf_bits(nv2_h) << 16);
                vp2[(size_t)rr * 64 + cp] = nq;
            }
        }
    }
}

// ---------------- readout ----------------
__global__ __launch_bounds__(128) void readout_kernel(
    const float* __restrict__ s, const int* __restrict__ batch,
    const float* __restrict__ lamW1, const float* __restrict__ lamb1,
    const float* __restrict__ lamW2, const float* __restrict__ lamb2,
    const float* __restrict__ phiW1, const float* __restrict__ phib1,
    const float* __restrict__ phiW2, const float* __restrict__ phib2,
    float* __restrict__ out)
{
    __shared__ int seg[2];
    __shared__ float hms[HD];
    __shared__ float red[HD];
    int m = blockIdx.x, c = threadIdx.x;
    if (c < 2) {
        int target = m + c;
        int lo = 0, hi = NA;
        while (lo < hi) { int mid = (lo + hi) >> 1; if (batch[mid] < target) lo = mid + 1; else hi = mid; }
        seg[c] = lo;
    }
    __syncthreads();
    int st = seg[0], en = seg[1];
    float acc = 0.f;
    for (int n2 = st; n2 < en; ++n2) acc += s[(size_t)n2 * HD + c];
    float hm = acc / (float)(en - st);
    hms[c] = hm;
    __syncthreads();

    float t = lamb1[c];
    for (int k = 0; k < HD; ++k) t += hms[k] * lamW1[k * HD + c];
    t = silu_f(t);
    red[c] = t * lamW2[c];
    __syncthreads();
    for (int off = 64; off > 0; off >>= 1) { if (c < off) red[c] += red[c + off]; __syncthreads(); }
    if (c == 0) out[m] = red[0] + lamb2[0];
    __syncthreads();

    t = phib1[c];
    for (int k = 0; k < HD; ++k) t += hms[k] * phiW1[k * HD + c];
    t = silu_f(t);
    red[c] = t * phiW2[c];
    __syncthreads();
    for (int off = 64; off > 0; off >>= 1) { if (c < off) red[c] += red[c + off]; __syncthreads(); }
    if (c == 0) { float x = red[0] + phib2[0]; out[NM + m] = 1.0f / (1.0f + __expf(-x)); }
}

// ---------------- host ----------------
extern "C" void kernel_launch(void* const* d_in, const int* in_sizes, int n_in,
                              void* d_out, int out_size, void* d_ws, size_t ws_size,
                              hipStream_t stream) {
    (void)in_sizes; (void)n_in; (void)out_size; (void)ws_size;
    const int*   z          = (const int*)  d_in[0];
    const float* pos        = (const float*)d_in[1];
    const int*   edge_index = (const int*)  d_in[2];
    const int*   batch      = (const int*)  d_in[3];
    const float* emb        = (const float*)d_in[4];
    const float* filt_W1    = (const float*)d_in[5];
    const float* filt_b1    = (const float*)d_in[6];
    const float* filt_W2    = (const float*)d_in[7];
    const float* filt_b2    = (const float*)d_in[8];
    const float* upd_W1     = (const float*)d_in[9];
    const float* upd_b1     = (const float*)d_in[10];
    const float* upd_W2     = (const float*)d_in[11];
    const float* upd_b2     = (const float*)d_in[12];
    const float* lam_W1     = (const float*)d_in[13];
    const float* lam_b1     = (const float*)d_in[14];
    const float* lam_W2     = (const float*)d_in[15];
    const float* lam_b2     = (const float*)d_in[16];
    const float* phi_W1     = (const float*)d_in[17];
    const float* phi_b1     = (const float*)d_in[18];
    const float* phi_W2     = (const float*)d_in[19];
    const float* phi_b2     = (const float*)d_in[20];
    float* out = (float*)d_out;

    const int* row = edge_index;
    const int* col = edge_index + NE;

    char* ws = (char*)d_ws;
    size_t off = 0;
    auto alloc = [&](size_t bytes) -> char* {
        char* p = ws + off;
        off = (off + bytes + 255) & ~(size_t)255;
        return p;
    };
    float* dist_g  = (float*)alloc((size_t)NE * 4);
    float* dirs    = (float*)alloc((size_t)NE * 3 * 4);
    int*   csr_eid = (int*)  alloc((size_t)NE * 4);
    int*   row_ptr = (int*)  alloc((size_t)(NA + 1) * 4);
    int*   deg     = (int*)  alloc((size_t)NA * 4);
    int*   cursor  = (int*)  alloc((size_t)NA * 4);
    int*   incl    = (int*)  alloc((size_t)NA * 4);
    int*   btot    = (int*)  alloc(256);
    int*   blist   = (int*)  alloc((size_t)BCAP * 4);
    int*   bcount  = (int*)  alloc(256);
    float* s       = (float*)alloc((size_t)NA * HD * 4);
    uint4* vp2     = (uint4*)alloc((size_t)NA * 64 * 16);
    float* m_s     = (float*)alloc((size_t)NA * HD * 4);
    float* m_v     = (float*)alloc((size_t)NA * HD * 3 * 4);
    unsigned short* fW1frag = (unsigned short*)alloc((size_t)NL * 8 * 64 * 8 * 2);
    unsigned short* fW2frag = (unsigned short*)alloc((size_t)NL * 24 * 4 * 64 * 8 * 2);
    unsigned short* uW1frag = (unsigned short*)alloc((size_t)NL * 8 * 12 * 64 * 8 * 2);
    unsigned short* uW2frag = (unsigned short*)alloc((size_t)NL * 24 * 4 * 64 * 8 * 2);

    const int EB = (NE + 255) / 256;
    const int SCAN_BLOCKS = (NA + 1023) / 1024;  // 49
    const int MSG_BLOCKS = NE / EPB;             // 12500 (exact)
    const int UPD_BLOCKS = (NA + 63) / 64;       // 782
    const int ZB_BLOCKS = (BCAP * 128) / 256;    // covers worst-case boundary count

    hipMemsetAsync(deg, 0, (size_t)NA * 4, stream);
    hipMemsetAsync(bcount, 0, 4, stream);
    geom_kernel<<<EB, 256, 0, stream>>>(pos, row, col, dist_g, dirs);
    deg_kernel<<<EB, 256, 0, stream>>>(row, deg);
    blockscan_kernel<<<SCAN_BLOCKS, 1024, 0, stream>>>(deg, incl, btot);
    totals_kernel<<<1, 64, 0, stream>>>(btot, SCAN_BLOCKS);
    finalize_kernel<<<(NA + 255) / 256, 256, 0, stream>>>(deg, incl, btot, row_ptr, cursor);
    mark_boundary_kernel<<<(NA + 255) / 256, 256, 0, stream>>>(row_ptr, blist, bcount);
    scatter_kernel<<<EB, 256, 0, stream>>>(row, cursor, csr_eid);
    embed_kernel<<<(NA * 64 + 255) / 256, 256, 0, stream>>>(z, emb, s, vp2);
    pack_w1frag_kernel<<<8, 256, 0, stream>>>(filt_W1, fW1frag);
    pack_bfrag_kernel<<<96, 256, 0, stream>>>(filt_W2, 128, 384, NL, fW2frag);
    pack_bfrag_kernel<<<96, 256, 0, stream>>>(upd_W1, 384, 128, NL, uW1frag);
    pack_bfrag_kernel<<<96, 256, 0, stream>>>(upd_W2, 128, 384, NL, uW2frag);

    for (int i = 0; i < NL; ++i) {
        const float* fb1 = filt_b1 + (size_t)i * HD;
        const float* fb2 = filt_b2 + (size_t)i * 384;
        const unsigned short* fW1f = fW1frag + (size_t)i * 8 * 64 * 8;
        const unsigned short* fW2f = fW2frag + (size_t)i * 24 * 4 * 64 * 8;
        const unsigned short* uW1f = uW1frag + (size_t)i * 8 * 12 * 64 * 8;
        const unsigned short* uW2f = uW2frag + (size_t)i * 24 * 4 * 64 * 8;
        const float* ub1 = upd_b1 + (size_t)i * HD;
        const float* ub2 = upd_b2 + (size_t)i * 384;

        zero_boundary_kernel<<<ZB_BLOCKS, 256, 0, stream>>>(blist, bcount, m_s, m_v);
        layer_msg_kernel<<<MSG_BLOCKS, 256, 0, stream>>>(
            dist_g, csr_eid, row_ptr, row, col, dirs,
            fW1f, fb1, fW2f, fb2, vp2, m_s, m_v);
        upd12_kernel<<<UPD_BLOCKS, 256, 0, stream>>>(
            s, vp2, m_s, m_v, uW1f, ub1, uW2f, ub2);
    }

    readout_kernel<<<NM, 128, 0, stream>>>(s, batch,
        lam_W1, lam_b1, lam_W2, lam_b2,
        phi_W1, phi_b1, phi_W2, phi_b2, out);
}